// Round 4
// baseline (421.875 us; speedup 1.0000x reference)
//
#include <hip/hip_runtime.h>

typedef unsigned short u16;
typedef unsigned int u32;
typedef short bf16x8 __attribute__((ext_vector_type(8)));
typedef float f32x4 __attribute__((ext_vector_type(4)));

#define B_ 2
#define L_ 2048
#define H_ 16
#define KV_ 4
#define D_ 128
#define HID_ 2048

// 1/sqrt(128) * log2(e): folded into Q so softmax runs in exp2 domain
#define QSCALE (0.08838834764831845f * 1.4426950408889634f)

__device__ __forceinline__ u16 f2bf(float f) {
  union { float f; u32 u; } v; v.f = f;
  u32 u = v.u;
  return (u16)((u + 0x7FFFu + ((u >> 16) & 1u)) >> 16);
}
__device__ __forceinline__ float bf2f(u16 h) {
  union { u32 u; float f; } v; v.u = ((u32)h) << 16;
  return v.f;
}
// pack two floats to bf16 pair (round-half-up; inputs are P in [0,1], no NaN/ovf)
__device__ __forceinline__ u32 pkbf(float a, float b) {
  union { float f; u32 u; } x, y; x.f = a; y.f = b;
  return ((x.u + 0x8000u) >> 16) | ((y.u + 0x8000u) & 0xffff0000u);
}
__device__ __forceinline__ void gl_lds16(const void* g, void* l) {
  __builtin_amdgcn_global_load_lds((__attribute__((address_space(1))) void*)(g),
                                   (__attribute__((address_space(3))) void*)(l),
                                   16, 0, 0);
}

// ---------------- fp32 -> bf16 plain convert (vectorized x4) ----------------
__global__ void k_f2b(const float* __restrict__ src, u16* __restrict__ dst, int n4) {
  int i = blockIdx.x * 256 + threadIdx.x;
  if (i >= n4) return;
  float4 v = ((const float4*)src)[i];
  u32 a = (u32)f2bf(v.x) | ((u32)f2bf(v.y) << 16);
  u32 b = (u32)f2bf(v.z) | ((u32)f2bf(v.w) << 16);
  ((uint2*)dst)[i] = make_uint2(a, b);
}

// ---------------- all weight transposes in one launch ----------------
// Wq(2048x2048), Wk(2048x512), Wv(2048x512) -> Wtqkv (3072x2048 packed); Wo -> Wto
__global__ void k_tconv_all(const float* __restrict__ Wq, const float* __restrict__ Wk,
                            const float* __restrict__ Wv, const float* __restrict__ Wo,
                            u16* __restrict__ Wtqkv, u16* __restrict__ Wto) {
  __shared__ float t[32][33];
  int id = blockIdx.x;
  const float* src; u16* dst; int C; int ct, rt;
  if (id < 4096)      { src = Wq; dst = Wtqkv;               C = 2048; ct = id & 63; rt = id >> 6; }
  else if (id < 5120) { id -= 4096; src = Wk; dst = Wtqkv + 2048 * 2048; C = 512; ct = id & 15; rt = id >> 4; }
  else if (id < 6144) { id -= 5120; src = Wv; dst = Wtqkv + 2560 * 2048; C = 512; ct = id & 15; rt = id >> 4; }
  else                { id -= 6144; src = Wo; dst = Wto;     C = 2048; ct = id & 63; rt = id >> 6; }
  const int R = 2048;
  int c0 = ct * 32, r0 = rt * 32;
  for (int i = threadIdx.y; i < 32; i += 8)
    t[i][threadIdx.x] = src[(size_t)(r0 + i) * C + c0 + threadIdx.x];
  __syncthreads();
  for (int i = threadIdx.y; i < 32; i += 8)
    dst[(size_t)(c0 + i) * R + r0 + threadIdx.x] = f2bf(t[threadIdx.x][i]);
}

// ---------------- bf16 GEMM: C(MxN) = A(MxK) @ Bt(NxK)^T ----------------
// 128x128 tile, BK=64, 4 waves, LDS-staged coalesced epilogue
template <int OUT_BF16>
__global__ __launch_bounds__(256, 2) void k_gemm_bt(
    const u16* __restrict__ A, const u16* __restrict__ Bt, void* __restrict__ Cv,
    int M, int N, int K) {
  __shared__ u16 As[128 * 64];
  __shared__ u16 Bs[128 * 64];
  __shared__ u16 Cs[128 * 136];  // epilogue staging (also used as float[64*132])
  const int tid = threadIdx.x;
  const int wave = tid >> 6, lane = tid & 63;
  const int wr = wave >> 1, wc = wave & 1;
  const int quad = lane >> 4, fm = lane & 15;
  const int m0 = blockIdx.y * 128, n0 = blockIdx.x * 128;
  f32x4 acc[4][4];
  for (int i = 0; i < 4; ++i)
    for (int j = 0; j < 4; ++j)
      for (int r = 0; r < 4; ++r) acc[i][j][r] = 0.0f;

  const int lrow = lane >> 3;
  const int lcol = (lane & 7) * 8;
  const int fk = quad * 8;

  for (int kt = 0; kt < K; kt += 64) {
    for (int p = 0; p < 4; ++p) {
      int roff = wave * 32 + p * 8 + lrow;
      gl_lds16(A + (size_t)(m0 + roff) * K + kt + lcol,
               As + wave * 2048 + p * 512 + lane * 8);
      gl_lds16(Bt + (size_t)(n0 + roff) * K + kt + lcol,
               Bs + wave * 2048 + p * 512 + lane * 8);
    }
    __syncthreads();
    for (int s = 0; s < 2; ++s) {
      bf16x8 af[4], bfr[4];
      for (int i = 0; i < 4; ++i)
        af[i] = *(const bf16x8*)(As + (wr * 64 + i * 16 + fm) * 64 + s * 32 + fk);
      for (int j = 0; j < 4; ++j)
        bfr[j] = *(const bf16x8*)(Bs + (wc * 64 + j * 16 + fm) * 64 + s * 32 + fk);
      for (int i = 0; i < 4; ++i)
        for (int j = 0; j < 4; ++j)
          acc[i][j] = __builtin_amdgcn_mfma_f32_16x16x32_bf16(af[i], bfr[j],
                                                              acc[i][j], 0, 0, 0);
    }
    __syncthreads();
  }

  if (OUT_BF16) {
    // stage whole 128x128 bf16 tile in LDS (pitch 136), then coalesced uint4 stores
    for (int i = 0; i < 4; ++i)
      for (int j = 0; j < 4; ++j)
        for (int r = 0; r < 4; ++r)
          Cs[(wr * 64 + i * 16 + quad * 4 + r) * 136 + wc * 64 + j * 16 + fm] =
              f2bf(acc[i][j][r]);
    __syncthreads();
    for (int it = 0; it < 8; ++it) {
      int row = it * 16 + (tid >> 4);
      int col = (tid & 15) * 8;
      uint4 v = *(const uint4*)(Cs + row * 136 + col);
      *(uint4*)((u16*)Cv + (size_t)(m0 + row) * N + n0 + col) = v;
    }
  } else {
    // fp32 out: two half-tiles of 64 rows through LDS (pitch 132 floats)
    float* Cf = (float*)Cs;
    for (int h = 0; h < 2; ++h) {
      if (h) __syncthreads();
      if (wr == h)
        for (int i = 0; i < 4; ++i)
          for (int j = 0; j < 4; ++j)
            for (int r = 0; r < 4; ++r)
              Cf[(i * 16 + quad * 4 + r) * 132 + wc * 64 + j * 16 + fm] =
                  acc[i][j][r];
      __syncthreads();
      for (int it = 0; it < 8; ++it) {
        int row = it * 8 + (tid >> 5);
        int col = (tid & 31) * 4;
        float4 v = *(const float4*)(Cf + row * 132 + col);
        *(float4*)((float*)Cv + (size_t)(m0 + h * 64 + row) * N + n0 + col) = v;
      }
    }
  }
}

// ---------------- RMSnorm + RoPE + layout shuffle ----------------
// q gets 1/sqrt(D)*log2e folded in; all outputs bf16
__global__ __launch_bounds__(256) void k_norm_rope(
    const u16* __restrict__ qkv, const float* __restrict__ cosp,
    const float* __restrict__ sinp, const float* __restrict__ qw,
    const float* __restrict__ kw, u16* __restrict__ Qb, u16* __restrict__ Kb,
    u16* __restrict__ Vtb) {
  int wid = blockIdx.x * 4 + (threadIdx.x >> 6);
  int lane = threadIdx.x & 63;
  int tok = wid / 24, unit = wid % 24;
  int b = tok >> 11, l = tok & 2047;
  const u16* row = qkv + (size_t)tok * 3072;
  int d0 = lane * 2;
  if (unit < 20) {
    int isq = unit < 16;
    int col = isq ? unit * 128 : 2048 + (unit - 16) * 128;
    u32 u = *(const u32*)(row + col + d0);
    float x0 = bf2f((u16)(u & 0xffff)), x1 = bf2f((u16)(u >> 16));
    float ss = x0 * x0 + x1 * x1;
    for (int m = 1; m < 64; m <<= 1) ss += __shfl_xor(ss, m);
    float rr = rsqrtf(ss * (1.0f / 128.0f) + 1e-6f);
    const float* wv = isq ? qw : kw;
    float n0 = x0 * rr * wv[d0], n1 = x1 * rr * wv[d0 + 1];
    float p0 = __shfl_xor(n0, 32), p1 = __shfl_xor(n1, 32);
    float sgn = (lane < 32) ? -1.0f : 1.0f;
    const float* cb = cosp + (size_t)tok * 128;
    const float* sb = sinp + (size_t)tok * 128;
    float o0 = n0 * cb[d0] + sgn * p0 * sb[d0];
    float o1 = n1 * cb[d0 + 1] + sgn * p1 * sb[d0 + 1];
    if (isq) {
      o0 *= QSCALE;
      o1 *= QSCALE;
      u32 packed = (u32)f2bf(o0) | ((u32)f2bf(o1) << 16);
      size_t off = (((size_t)(b * H_ + unit)) * L_ + l) * D_ + d0;
      *(u32*)(Qb + off) = packed;
    } else {
      u32 packed = (u32)f2bf(o0) | ((u32)f2bf(o1) << 16);
      size_t off = (((size_t)(b * KV_ + (unit - 16))) * L_ + l) * D_ + d0;
      *(u32*)(Kb + off) = packed;
    }
  } else {
    // v: transpose to (B,KV,D,L), stays bf16
    int g = unit - 20;
    size_t base = (((size_t)(b * KV_ + g)) * D_ + d0) * L_ + l;
    Vtb[base] = row[2560 + g * 128 + d0];
    Vtb[base + L_] = row[2560 + g * 128 + d0 + 1];
  }
}

// ---------------- flash attention (S^T formulation, K=32 PV) ----------------
// S^T = K Q^T (C-frags: col=q=fm, rows=keys=16n+4quad+r)
// PV: P^T C-frag regs fed DIRECTLY as K=32 bf16 A-operand (contraction order is
// arbitrary as long as B matches): A elems j=0..7 at lane quad hold keys
// 32ks2+4quad+{0..3} and +16+{0..3}; B (V) reads the same keys from the
// swizzled Vt tile as two b64s. O comes out non-transposed (rows q=quad*4+r).
__global__ __launch_bounds__(256, 4) void k_attn(const u16* __restrict__ Qb,
                                                 const u16* __restrict__ Kb,
                                                 const u16* __restrict__ Vtb,
                                                 u16* __restrict__ AO) {
  __shared__ u16 smem[16384];  // Ks 64x128 (8192), Vs 128x64 (8192)
  u16* Ks = smem;
  u16* Vs = smem + 8192;
  const int tid = threadIdx.x, wave = tid >> 6, lane = tid & 63;
  const int quad = lane >> 4, fm = lane & 15;
  const int f7 = fm & 7;
  const int qt = blockIdx.x, bh = blockIdx.y;
  const int b = bh >> 4, h = bh & 15, g = h >> 2;
  const u16* Kg = Kb + ((size_t)(b * KV_ + g)) * L_ * D_;
  const u16* Vg = Vtb + ((size_t)(b * KV_ + g)) * D_ * L_;

  // Q B-frags straight from global: q = qt*64 + wave*16 + fm, d = ks*32+quad*8+{0..7}
  const u16* Qg = Qb + ((size_t)bh * L_ + qt * 64 + wave * 16 + fm) * D_;
  bf16x8 qf[4];
  for (int ks = 0; ks < 4; ++ks)
    qf[ks] = *(const bf16x8*)(Qg + ks * 32 + quad * 8);

  f32x4 o[8];  // O frag f: col d=f*16+fm, row q=quad*4+r
  for (int f = 0; f < 8; ++f)
    for (int r = 0; r < 4; ++r) o[f][r] = 0.0f;
  float mrun = -1.0e30f, lrun = 0.0f;  // per-lane softmax state for q = fm

  const int eK = wave * 2048 + (lane << 3);
  const int cK = lane & 15;
  const int cV = lane & 7;
  for (int kt = 0; kt < 32; ++kt) {
    __syncthreads();
    for (int p = 0; p < 4; ++p) {
      int e = eK + p * 512;
      int rowK = e >> 7;
      int gK = (cK & 8) | ((cK & 7) ^ (rowK & 7));
      gl_lds16(Kg + (size_t)(kt * 64 + rowK) * 128 + gK * 8, Ks + e);
      int rowV = e >> 6;
      int gV = cV ^ (rowV & 7);
      gl_lds16(Vg + (size_t)rowV * L_ + kt * 64 + gV * 8, Vs + e);
    }
    __syncthreads();

    // S^T = K Q^T
    f32x4 s[4];
    for (int n = 0; n < 4; ++n)
      for (int r = 0; r < 4; ++r) s[n][r] = 0.0f;
    for (int ks = 0; ks < 4; ++ks) {
      int c = 4 * ks + quad;
      int cp = (c & 8) | ((c & 7) ^ f7);
      for (int n = 0; n < 4; ++n) {
        bf16x8 kf = *(const bf16x8*)(Ks + (n * 16 + fm) * 128 + cp * 8);
        s[n] = __builtin_amdgcn_mfma_f32_16x16x32_bf16(kf, qf[ks], s[n], 0, 0, 0);
      }
    }

    // online softmax (per-lane q = fm; cross-quad via 2 shuffles)
    f32x4 m4 = s[0];
    for (int n = 1; n < 4; ++n)
      for (int r = 0; r < 4; ++r) m4[r] = fmaxf(m4[r], s[n][r]);
    float pm = fmaxf(fmaxf(m4[0], m4[1]), fmaxf(m4[2], m4[3]));
    pm = fmaxf(pm, __shfl_xor(pm, 16));
    pm = fmaxf(pm, __shfl_xor(pm, 32));
    float mn = fmaxf(mrun, pm);
    float al = __builtin_amdgcn_exp2f(mrun - mn);
    mrun = mn;
    float rs = 0.0f;
    u32 pk[4][2];  // P^T frag n packed: keys 16n+4quad+{0,1} / {2,3}
    for (int n = 0; n < 4; ++n) {
      float p0 = __builtin_amdgcn_exp2f(s[n][0] - mn);
      float p1 = __builtin_amdgcn_exp2f(s[n][1] - mn);
      float p2 = __builtin_amdgcn_exp2f(s[n][2] - mn);
      float p3 = __builtin_amdgcn_exp2f(s[n][3] - mn);
      rs += (p0 + p1) + (p2 + p3);
      pk[n][0] = pkbf(p0, p1);
      pk[n][1] = pkbf(p2, p3);
    }
    rs += __shfl_xor(rs, 16);
    rs += __shfl_xor(rs, 32);
    lrun = lrun * al + rs;
    if (__any(al != 1.0f)) {
      // O rows are q = quad*4+r: fetch alphas from lanes fm' = quad*4+r
      float a0 = __shfl(al, (lane & 48) | (quad * 4 + 0));
      float a1 = __shfl(al, (lane & 48) | (quad * 4 + 1));
      float a2 = __shfl(al, (lane & 48) | (quad * 4 + 2));
      float a3 = __shfl(al, (lane & 48) | (quad * 4 + 3));
      for (int f = 0; f < 8; ++f) {
        o[f][0] *= a0; o[f][1] *= a1; o[f][2] *= a2; o[f][3] *= a3;
      }
    }

    // O += P V via K=32 bf16: A = pk regs directly, B = matching V keys
    for (int ks2 = 0; ks2 < 2; ++ks2) {
      union { u32 u[4]; bf16x8 v; } pa;
      pa.u[0] = pk[2 * ks2][0];
      pa.u[1] = pk[2 * ks2][1];
      pa.u[2] = pk[2 * ks2 + 1][0];
      pa.u[3] = pk[2 * ks2 + 1][1];
      int c1 = (4 * ks2 + (quad >> 1)) ^ f7;
      int c2 = (4 * ks2 + (quad >> 1) + 2) ^ f7;
      int half = (quad & 1) * 4;
      for (int f = 0; f < 8; ++f) {
        const u16* vrow = Vs + (f * 16 + fm) * 64;
        uint2 vb0 = *(const uint2*)(vrow + c1 * 8 + half);
        uint2 vb1 = *(const uint2*)(vrow + c2 * 8 + half);
        union { u32 u[4]; bf16x8 v; } vv;
        vv.u[0] = vb0.x; vv.u[1] = vb0.y; vv.u[2] = vb1.x; vv.u[3] = vb1.y;
        o[f] = __builtin_amdgcn_mfma_f32_16x16x32_bf16(pa.v, vv.v, o[f], 0, 0, 0);
      }
    }
  }

  // epilogue: lane holds O[q=quad*4+r][d=f*16+fm] -> LDS (pitch 136) -> coalesced
  __syncthreads();
  float li = 1.0f / lrun;
  float l0 = __shfl(li, (lane & 48) | (quad * 4 + 0));
  float l1 = __shfl(li, (lane & 48) | (quad * 4 + 1));
  float l2 = __shfl(li, (lane & 48) | (quad * 4 + 2));
  float l3 = __shfl(li, (lane & 48) | (quad * 4 + 3));
  for (int f = 0; f < 8; ++f) {
    int e = (wave * 16 + quad * 4) * 136 + f * 16 + fm;
    smem[e] = f2bf(o[f][0] * l0);
    smem[e + 136] = f2bf(o[f][1] * l1);
    smem[e + 272] = f2bf(o[f][2] * l2);
    smem[e + 408] = f2bf(o[f][3] * l3);
  }
  __syncthreads();
  const size_t tok0 = (size_t)b * L_ + qt * 64;
  for (int it = 0; it < 8; ++it) {
    int rrow = wave * 16 + it * 2 + (lane >> 5);
    int cc = (lane & 31) * 4;
    uint2 v = *(const uint2*)(smem + rrow * 136 + cc);
    *(uint2*)(AO + (tok0 + rrow) * (H_ * D_) + h * D_ + cc) = v;
  }
}

// ---------------- launcher ----------------
extern "C" void kernel_launch(void* const* d_in, const int* in_sizes, int n_in,
                              void* d_out, int out_size, void* d_ws,
                              size_t ws_size, hipStream_t stream) {
  const float* hidden = (const float*)d_in[0];
  const float* cosp = (const float*)d_in[1];
  const float* sinp = (const float*)d_in[2];
  const float* Wq = (const float*)d_in[3];
  const float* Wk = (const float*)d_in[4];
  const float* Wv = (const float*)d_in[5];
  const float* Wo = (const float*)d_in[6];
  const float* qw = (const float*)d_in[7];
  const float* kw = (const float*)d_in[8];
  float* out = (float*)d_out;

  char* w = (char*)d_ws;
  u16* Xb = (u16*)(w);                          // 4096x2048 bf16, 16MB
  u16* Wtqkv = (u16*)(w + (16u << 20));         // 3072x2048 bf16, 12MB
  u16* Wto = (u16*)(w + (28u << 20));           // 2048x2048 bf16, 8MB
  u16* qkv = (u16*)(w + (36u << 20));           // 4096x3072 bf16, 24MB
  u16* Qb = (u16*)(w + (60u << 20));            // 16MB
  u16* Kb = (u16*)(w + (76u << 20));            // 4MB
  u16* Vtb = (u16*)(w + (80u << 20));           // 4MB bf16 (ends 84MB)
  u16* AO = Xb;                                 // reuse after GEMM1

  k_f2b<<<8192, 256, 0, stream>>>(hidden, Xb, 2097152);
  k_tconv_all<<<10240, dim3(32, 8), 0, stream>>>(Wq, Wk, Wv, Wo, Wtqkv, Wto);
  k_gemm_bt<1><<<dim3(24, 32), 256, 0, stream>>>(Xb, Wtqkv, qkv, 4096, 3072, 2048);
  k_norm_rope<<<24576, 256, 0, stream>>>(qkv, cosp, sinp, qw, kw, Qb, Kb, Vtb);
  k_attn<<<dim3(32, 32), 256, 0, stream>>>(Qb, Kb, Vtb, AO);
  k_gemm_bt<0><<<dim3(16, 32), 256, 0, stream>>>(AO, Wto, out, 4096, 2048, 2048);
}

// Round 5
// 363.677 us; speedup vs baseline: 1.1600x; 1.1600x over previous
//
#include <hip/hip_runtime.h>

typedef unsigned short u16;
typedef unsigned int u32;
typedef short bf16x8 __attribute__((ext_vector_type(8)));
typedef float f32x4 __attribute__((ext_vector_type(4)));

#define B_ 2
#define L_ 2048
#define H_ 16
#define KV_ 4
#define D_ 128
#define HID_ 2048

// 1/sqrt(128) * log2(e): folded into Q so softmax runs in exp2 domain
#define QSCALE (0.08838834764831845f * 1.4426950408889634f)
// fixed softmax max: |s| <= 128*scale*log2e = 16.34 (Cauchy-Schwarz on rms-normed q,k)
#define SMAX 17.0f

__device__ __forceinline__ u16 f2bf(float f) {
  union { float f; u32 u; } v; v.f = f;
  u32 u = v.u;
  return (u16)((u + 0x7FFFu + ((u >> 16) & 1u)) >> 16);
}
__device__ __forceinline__ float bf2f(u16 h) {
  union { u32 u; float f; } v; v.u = ((u32)h) << 16;
  return v.f;
}
// pack two floats to bf16 pair (round-half-up; inputs are P in [0,1], no NaN/ovf)
__device__ __forceinline__ u32 pkbf(float a, float b) {
  union { float f; u32 u; } x, y; x.f = a; y.f = b;
  return ((x.u + 0x8000u) >> 16) | ((y.u + 0x8000u) & 0xffff0000u);
}
__device__ __forceinline__ void gl_lds16(const void* g, void* l) {
  __builtin_amdgcn_global_load_lds((__attribute__((address_space(1))) void*)(g),
                                   (__attribute__((address_space(3))) void*)(l),
                                   16, 0, 0);
}

// ---------------- fp32 -> bf16 plain convert (vectorized x4) ----------------
__global__ void k_f2b(const float* __restrict__ src, u16* __restrict__ dst, int n4) {
  int i = blockIdx.x * 256 + threadIdx.x;
  if (i >= n4) return;
  float4 v = ((const float4*)src)[i];
  u32 a = (u32)f2bf(v.x) | ((u32)f2bf(v.y) << 16);
  u32 b = (u32)f2bf(v.z) | ((u32)f2bf(v.w) << 16);
  ((uint2*)dst)[i] = make_uint2(a, b);
}

// ---------------- all weight transposes in one launch ----------------
__global__ void k_tconv_all(const float* __restrict__ Wq, const float* __restrict__ Wk,
                            const float* __restrict__ Wv, const float* __restrict__ Wo,
                            u16* __restrict__ Wtqkv, u16* __restrict__ Wto) {
  __shared__ float t[32][33];
  int id = blockIdx.x;
  const float* src; u16* dst; int C; int ct, rt;
  if (id < 4096)      { src = Wq; dst = Wtqkv;               C = 2048; ct = id & 63; rt = id >> 6; }
  else if (id < 5120) { id -= 4096; src = Wk; dst = Wtqkv + 2048 * 2048; C = 512; ct = id & 15; rt = id >> 4; }
  else if (id < 6144) { id -= 5120; src = Wv; dst = Wtqkv + 2560 * 2048; C = 512; ct = id & 15; rt = id >> 4; }
  else                { id -= 6144; src = Wo; dst = Wto;     C = 2048; ct = id & 63; rt = id >> 6; }
  const int R = 2048;
  int c0 = ct * 32, r0 = rt * 32;
  for (int i = threadIdx.y; i < 32; i += 8)
    t[i][threadIdx.x] = src[(size_t)(r0 + i) * C + c0 + threadIdx.x];
  __syncthreads();
  for (int i = threadIdx.y; i < 32; i += 8)
    dst[(size_t)(c0 + i) * R + r0 + threadIdx.x] = f2bf(t[threadIdx.x][i]);
}

// ---------------- bf16 GEMM: C(MxN) = A(MxK) @ Bt(NxK)^T ----------------
// 128x128 tile, BK=64, 4 waves; epilogue stages through the SAME 32KB LDS
// (multi-pass) so occupancy is unchanged while stores are fully coalesced.
template <int OUT_BF16>
__global__ __launch_bounds__(256, 2) void k_gemm_bt(
    const u16* __restrict__ A, const u16* __restrict__ Bt, void* __restrict__ Cv,
    int M, int N, int K) {
  __shared__ u16 smem[16384];  // As = [0:8192), Bs = [8192:16384)
  u16* As = smem;
  u16* Bs = smem + 8192;
  const int tid = threadIdx.x;
  const int wave = tid >> 6, lane = tid & 63;
  const int wr = wave >> 1, wc = wave & 1;
  const int quad = lane >> 4, fm = lane & 15;
  const int m0 = blockIdx.y * 128, n0 = blockIdx.x * 128;
  f32x4 acc[4][4];
  for (int i = 0; i < 4; ++i)
    for (int j = 0; j < 4; ++j)
      for (int r = 0; r < 4; ++r) acc[i][j][r] = 0.0f;

  const int lrow = lane >> 3;
  const int lcol = (lane & 7) * 8;
  const int fk = quad * 8;

  for (int kt = 0; kt < K; kt += 64) {
    for (int p = 0; p < 4; ++p) {
      int roff = wave * 32 + p * 8 + lrow;
      gl_lds16(A + (size_t)(m0 + roff) * K + kt + lcol,
               As + wave * 2048 + p * 512 + lane * 8);
      gl_lds16(Bt + (size_t)(n0 + roff) * K + kt + lcol,
               Bs + wave * 2048 + p * 512 + lane * 8);
    }
    __syncthreads();
    for (int s = 0; s < 2; ++s) {
      bf16x8 af[4], bfr[4];
      for (int i = 0; i < 4; ++i)
        af[i] = *(const bf16x8*)(As + (wr * 64 + i * 16 + fm) * 64 + s * 32 + fk);
      for (int j = 0; j < 4; ++j)
        bfr[j] = *(const bf16x8*)(Bs + (wc * 64 + j * 16 + fm) * 64 + s * 32 + fk);
      for (int i = 0; i < 4; ++i)
        for (int j = 0; j < 4; ++j)
          acc[i][j] = __builtin_amdgcn_mfma_f32_16x16x32_bf16(af[i], bfr[j],
                                                              acc[i][j], 0, 0, 0);
    }
    __syncthreads();
  }

  if (OUT_BF16) {
    // two half-tile passes: 64 rows x pitch 136 u16 = 17.4KB <= 32KB
    u16* Cs = smem;
    for (int hh = 0; hh < 2; ++hh) {
      if (hh) __syncthreads();
      if (wr == hh)
        for (int i = 0; i < 4; ++i)
          for (int j = 0; j < 4; ++j)
            for (int r = 0; r < 4; ++r)
              Cs[(i * 16 + quad * 4 + r) * 136 + wc * 64 + j * 16 + fm] =
                  f2bf(acc[i][j][r]);
      __syncthreads();
      for (int it = 0; it < 4; ++it) {
        int row = it * 16 + (tid >> 4);
        int col = (tid & 15) * 8;
        uint4 v = *(const uint4*)(Cs + row * 136 + col);
        *(uint4*)((u16*)Cv + (size_t)(m0 + hh * 64 + row) * N + n0 + col) = v;
      }
    }
  } else {
    // four quarter-tile passes: 32 rows x pitch 132 fp32 = 16.9KB <= 32KB
    float* Cf = (float*)smem;
    for (int p = 0; p < 4; ++p) {
      if (p) __syncthreads();
      if (wr == (p >> 1))
        for (int ii = 0; ii < 2; ++ii) {
          int i = 2 * (p & 1) + ii;
          for (int j = 0; j < 4; ++j)
            for (int r = 0; r < 4; ++r)
              Cf[(ii * 16 + quad * 4 + r) * 132 + wc * 64 + j * 16 + fm] =
                  acc[i][j][r];
        }
      __syncthreads();
      for (int it = 0; it < 4; ++it) {
        int row = it * 8 + (tid >> 5);
        int col = (tid & 31) * 4;
        float4 v = *(const float4*)(Cf + row * 132 + col);
        *(float4*)((float*)Cv + (size_t)(m0 + p * 32 + row) * N + n0 + col) = v;
      }
    }
  }
}

// ---------------- RMSnorm + RoPE + layout shuffle ----------------
// q gets 1/sqrt(D)*log2e folded in. V is written transposed (B,KV,D,L) with the
// key (l) index BIT-PERMUTED within 32-token groups so that the attention PV
// B-fragment (keys 32ks2+16(j>>2)+4quad+(j&3)) is one contiguous b128:
//   l = 32a+16b+4c+d  ->  lp = 32a+8c+4b+d
__global__ __launch_bounds__(256) void k_norm_rope(
    const u16* __restrict__ qkv, const float* __restrict__ cosp,
    const float* __restrict__ sinp, const float* __restrict__ qw,
    const float* __restrict__ kw, u16* __restrict__ Qb, u16* __restrict__ Kb,
    u16* __restrict__ Vtb) {
  int wid = blockIdx.x * 4 + (threadIdx.x >> 6);
  int lane = threadIdx.x & 63;
  int tok = wid / 24, unit = wid % 24;
  int b = tok >> 11, l = tok & 2047;
  const u16* row = qkv + (size_t)tok * 3072;
  int d0 = lane * 2;
  if (unit < 20) {
    int isq = unit < 16;
    int col = isq ? unit * 128 : 2048 + (unit - 16) * 128;
    u32 u = *(const u32*)(row + col + d0);
    float x0 = bf2f((u16)(u & 0xffff)), x1 = bf2f((u16)(u >> 16));
    float ss = x0 * x0 + x1 * x1;
    for (int m = 1; m < 64; m <<= 1) ss += __shfl_xor(ss, m);
    float rr = rsqrtf(ss * (1.0f / 128.0f) + 1e-6f);
    const float* wv = isq ? qw : kw;
    float n0 = x0 * rr * wv[d0], n1 = x1 * rr * wv[d0 + 1];
    float p0 = __shfl_xor(n0, 32), p1 = __shfl_xor(n1, 32);
    float sgn = (lane < 32) ? -1.0f : 1.0f;
    const float* cb = cosp + (size_t)tok * 128;
    const float* sb = sinp + (size_t)tok * 128;
    float o0 = n0 * cb[d0] + sgn * p0 * sb[d0];
    float o1 = n1 * cb[d0 + 1] + sgn * p1 * sb[d0 + 1];
    if (isq) {
      o0 *= QSCALE;
      o1 *= QSCALE;
      u32 packed = (u32)f2bf(o0) | ((u32)f2bf(o1) << 16);
      size_t off = (((size_t)(b * H_ + unit)) * L_ + l) * D_ + d0;
      *(u32*)(Qb + off) = packed;
    } else {
      u32 packed = (u32)f2bf(o0) | ((u32)f2bf(o1) << 16);
      size_t off = (((size_t)(b * KV_ + (unit - 16))) * L_ + l) * D_ + d0;
      *(u32*)(Kb + off) = packed;
    }
  } else {
    // v: transpose to (B,KV,D,L) with permuted l
    int g = unit - 20;
    int lp = (l & ~31) | (((l >> 2) & 3) << 3) | (((l >> 4) & 1) << 2) | (l & 3);
    size_t base = (((size_t)(b * KV_ + g)) * D_ + d0) * L_ + lp;
    Vtb[base] = row[2560 + g * 128 + d0];
    Vtb[base + L_] = row[2560 + g * 128 + d0 + 1];
  }
}

// ---------------- flash attention (S^T, fixed-max softmax, K=32 PV) ----------------
// S^T = K Q^T (C-frags: col=q=fm, rows=keys=16n+4quad+r).
// Fixed softmax max (SMAX): no per-tile max reduction, no O rescale, no shuffles
// in the K-loop; lrun accumulates lane-locally, reduced once at the end.
// PV: P^T C-frag regs fed directly as the K=32 bf16 A-operand; V tile is stored
// column-permuted so the matching B-frag is one contiguous (swizzled) b128.
__global__ __launch_bounds__(256, 4) void k_attn(const u16* __restrict__ Qb,
                                                 const u16* __restrict__ Kb,
                                                 const u16* __restrict__ Vtb,
                                                 u16* __restrict__ AO) {
  __shared__ u16 smem[16384];  // Ks 64x128 (8192), Vs 128x64 (8192)
  u16* Ks = smem;
  u16* Vs = smem + 8192;
  const int tid = threadIdx.x, wave = tid >> 6, lane = tid & 63;
  const int quad = lane >> 4, fm = lane & 15;
  const int f7 = fm & 7;
  const int qt = blockIdx.x, bh = blockIdx.y;
  const int b = bh >> 4, h = bh & 15, g = h >> 2;
  const u16* Kg = Kb + ((size_t)(b * KV_ + g)) * L_ * D_;
  const u16* Vg = Vtb + ((size_t)(b * KV_ + g)) * D_ * L_;

  // Q B-frags straight from global: q = qt*64 + wave*16 + fm, d = ks*32+quad*8+{0..7}
  const u16* Qg = Qb + ((size_t)bh * L_ + qt * 64 + wave * 16 + fm) * D_;
  bf16x8 qf[4];
  for (int ks = 0; ks < 4; ++ks)
    qf[ks] = *(const bf16x8*)(Qg + ks * 32 + quad * 8);

  f32x4 o[8];  // O frag f: col d=f*16+fm, row q=quad*4+r
  for (int f = 0; f < 8; ++f)
    for (int r = 0; r < 4; ++r) o[f][r] = 0.0f;
  float lrun = 0.0f;  // per-lane partial denominator for q = fm (16 keys/tile)

  const int eK = wave * 2048 + (lane << 3);
  const int cK = lane & 15;
  const int cV = lane & 7;
  for (int kt = 0; kt < 32; ++kt) {
    __syncthreads();
    for (int p = 0; p < 4; ++p) {
      int e = eK + p * 512;
      int rowK = e >> 7;
      int gK = (cK & 8) | ((cK & 7) ^ (rowK & 7));
      gl_lds16(Kg + (size_t)(kt * 64 + rowK) * 128 + gK * 8, Ks + e);
      int rowV = e >> 6;
      int gV = cV ^ (rowV & 7);
      gl_lds16(Vg + (size_t)rowV * L_ + kt * 64 + gV * 8, Vs + e);
    }
    __syncthreads();

    // S^T = K Q^T
    f32x4 s[4];
    for (int n = 0; n < 4; ++n)
      for (int r = 0; r < 4; ++r) s[n][r] = 0.0f;
    for (int ks = 0; ks < 4; ++ks) {
      int c = 4 * ks + quad;
      int cp = (c & 8) | ((c & 7) ^ f7);
      for (int n = 0; n < 4; ++n) {
        bf16x8 kf = *(const bf16x8*)(Ks + (n * 16 + fm) * 128 + cp * 8);
        s[n] = __builtin_amdgcn_mfma_f32_16x16x32_bf16(kf, qf[ks], s[n], 0, 0, 0);
      }
    }

    // fixed-max softmax: P = exp2(s - SMAX), no reductions in the loop
    u32 pk[4][2];
    float rs = 0.0f;
    for (int n = 0; n < 4; ++n) {
      float p0 = __builtin_amdgcn_exp2f(s[n][0] - SMAX);
      float p1 = __builtin_amdgcn_exp2f(s[n][1] - SMAX);
      float p2 = __builtin_amdgcn_exp2f(s[n][2] - SMAX);
      float p3 = __builtin_amdgcn_exp2f(s[n][3] - SMAX);
      rs += (p0 + p1) + (p2 + p3);
      pk[n][0] = pkbf(p0, p1);
      pk[n][1] = pkbf(p2, p3);
    }
    lrun += rs;

    // O += P V via K=32 bf16: A = pk regs directly, B = one swizzled b128
    for (int ks2 = 0; ks2 < 2; ++ks2) {
      union { u32 u[4]; bf16x8 v; } pa;
      pa.u[0] = pk[2 * ks2][0];
      pa.u[1] = pk[2 * ks2][1];
      pa.u[2] = pk[2 * ks2 + 1][0];
      pa.u[3] = pk[2 * ks2 + 1][1];
      int chunk = (4 * ks2 + quad) ^ f7;
      for (int f = 0; f < 8; ++f) {
        bf16x8 vv = *(const bf16x8*)(Vs + (f * 16 + fm) * 64 + chunk * 8);
        o[f] = __builtin_amdgcn_mfma_f32_16x16x32_bf16(pa.v, vv, o[f], 0, 0, 0);
      }
    }
  }

  // final denominator: reduce lrun across quads (all lanes with same fm)
  lrun += __shfl_xor(lrun, 16);
  lrun += __shfl_xor(lrun, 32);
  float li = 1.0f / lrun;
  // O rows are q = quad*4+r: fetch 1/l from lanes fm' = quad*4+r
  float l0 = __shfl(li, (lane & 48) | (quad * 4 + 0));
  float l1 = __shfl(li, (lane & 48) | (quad * 4 + 1));
  float l2 = __shfl(li, (lane & 48) | (quad * 4 + 2));
  float l3 = __shfl(li, (lane & 48) | (quad * 4 + 3));
  __syncthreads();
  for (int f = 0; f < 8; ++f) {
    int e = (wave * 16 + quad * 4) * 136 + f * 16 + fm;
    smem[e] = f2bf(o[f][0] * l0);
    smem[e + 136] = f2bf(o[f][1] * l1);
    smem[e + 272] = f2bf(o[f][2] * l2);
    smem[e + 408] = f2bf(o[f][3] * l3);
  }
  __syncthreads();
  const size_t tok0 = (size_t)b * L_ + qt * 64;
  for (int it = 0; it < 8; ++it) {
    int rrow = wave * 16 + it * 2 + (lane >> 5);
    int cc = (lane & 31) * 4;
    uint2 v = *(const uint2*)(smem + rrow * 136 + cc);
    *(uint2*)(AO + (tok0 + rrow) * (H_ * D_) + h * D_ + cc) = v;
  }
}

// ---------------- launcher ----------------
extern "C" void kernel_launch(void* const* d_in, const int* in_sizes, int n_in,
                              void* d_out, int out_size, void* d_ws,
                              size_t ws_size, hipStream_t stream) {
  const float* hidden = (const float*)d_in[0];
  const float* cosp = (const float*)d_in[1];
  const float* sinp = (const float*)d_in[2];
  const float* Wq = (const float*)d_in[3];
  const float* Wk = (const float*)d_in[4];
  const float* Wv = (const float*)d_in[5];
  const float* Wo = (const float*)d_in[6];
  const float* qw = (const float*)d_in[7];
  const float* kw = (const float*)d_in[8];
  float* out = (float*)d_out;

  char* w = (char*)d_ws;
  u16* Xb = (u16*)(w);                          // 4096x2048 bf16, 16MB
  u16* Wtqkv = (u16*)(w + (16u << 20));         // 3072x2048 bf16, 12MB
  u16* Wto = (u16*)(w + (28u << 20));           // 2048x2048 bf16, 8MB
  u16* qkv = (u16*)(w + (36u << 20));           // 4096x3072 bf16, 24MB
  u16* Qb = (u16*)(w + (60u << 20));            // 16MB
  u16* Kb = (u16*)(w + (76u << 20));            // 4MB
  u16* Vtb = (u16*)(w + (80u << 20));           // 4MB bf16 (ends 84MB)
  u16* AO = Xb;                                 // reuse after GEMM1

  k_f2b<<<8192, 256, 0, stream>>>(hidden, Xb, 2097152);
  k_tconv_all<<<10240, dim3(32, 8), 0, stream>>>(Wq, Wk, Wv, Wo, Wtqkv, Wto);
  k_gemm_bt<1><<<dim3(24, 32), 256, 0, stream>>>(Xb, Wtqkv, qkv, 4096, 3072, 2048);
  k_norm_rope<<<24576, 256, 0, stream>>>(qkv, cosp, sinp, qw, kw, Qb, Kb, Vtb);
  k_attn<<<dim3(32, 32), 256, 0, stream>>>(Qb, Kb, Vtb, AO);
  k_gemm_bt<0><<<dim3(16, 32), 256, 0, stream>>>(AO, Wto, out, 4096, 2048, 2048);
}

// Round 6
// 339.766 us; speedup vs baseline: 1.2417x; 1.0704x over previous
//
#include <hip/hip_runtime.h>

typedef unsigned short u16;
typedef unsigned int u32;
typedef short bf16x8 __attribute__((ext_vector_type(8)));
typedef float f32x4 __attribute__((ext_vector_type(4)));

#define B_ 2
#define L_ 2048
#define H_ 16
#define KV_ 4
#define D_ 128
#define HID_ 2048

// 1/sqrt(128) * log2(e): folded into Q so softmax runs in exp2 domain
#define QSCALE (0.08838834764831845f * 1.4426950408889634f)
// fixed softmax max: |s| <= 128*scale*log2e = 16.34 (Cauchy-Schwarz on rms-normed q,k)
#define SMAX 17.0f

__device__ __forceinline__ u16 f2bf(float f) {
  union { float f; u32 u; } v; v.f = f;
  u32 u = v.u;
  return (u16)((u + 0x7FFFu + ((u >> 16) & 1u)) >> 16);
}
__device__ __forceinline__ float bf2f(u16 h) {
  union { u32 u; float f; } v; v.u = ((u32)h) << 16;
  return v.f;
}
// pack two floats to bf16 pair (round-half-up; inputs are P in [0,1], no NaN/ovf)
__device__ __forceinline__ u32 pkbf(float a, float b) {
  union { float f; u32 u; } x, y; x.f = a; y.f = b;
  return ((x.u + 0x8000u) >> 16) | ((y.u + 0x8000u) & 0xffff0000u);
}
__device__ __forceinline__ void gl_lds16(const void* g, void* l) {
  __builtin_amdgcn_global_load_lds((__attribute__((address_space(1))) void*)(g),
                                   (__attribute__((address_space(3))) void*)(l),
                                   16, 0, 0);
}

// ---------------- fp32 -> bf16 plain convert (vectorized x4) ----------------
__global__ void k_f2b(const float* __restrict__ src, u16* __restrict__ dst, int n4) {
  int i = blockIdx.x * 256 + threadIdx.x;
  if (i >= n4) return;
  float4 v = ((const float4*)src)[i];
  u32 a = (u32)f2bf(v.x) | ((u32)f2bf(v.y) << 16);
  u32 b = (u32)f2bf(v.z) | ((u32)f2bf(v.w) << 16);
  ((uint2*)dst)[i] = make_uint2(a, b);
}

// ---------------- all weight transposes in one launch ----------------
__global__ void k_tconv_all(const float* __restrict__ Wq, const float* __restrict__ Wk,
                            const float* __restrict__ Wv, const float* __restrict__ Wo,
                            u16* __restrict__ Wtqkv, u16* __restrict__ Wto) {
  __shared__ float t[32][33];
  int id = blockIdx.x;
  const float* src; u16* dst; int C; int ct, rt;
  if (id < 4096)      { src = Wq; dst = Wtqkv;               C = 2048; ct = id & 63; rt = id >> 6; }
  else if (id < 5120) { id -= 4096; src = Wk; dst = Wtqkv + 2048 * 2048; C = 512; ct = id & 15; rt = id >> 4; }
  else if (id < 6144) { id -= 5120; src = Wv; dst = Wtqkv + 2560 * 2048; C = 512; ct = id & 15; rt = id >> 4; }
  else                { id -= 6144; src = Wo; dst = Wto;     C = 2048; ct = id & 63; rt = id >> 6; }
  const int R = 2048;
  int c0 = ct * 32, r0 = rt * 32;
  for (int i = threadIdx.y; i < 32; i += 8)
    t[i][threadIdx.x] = src[(size_t)(r0 + i) * C + c0 + threadIdx.x];
  __syncthreads();
  for (int i = threadIdx.y; i < 32; i += 8)
    dst[(size_t)(c0 + i) * R + r0 + threadIdx.x] = f2bf(t[threadIdx.x][i]);
}

// ---------------- bf16 GEMM: C(MxN) = A(MxK) @ Bt(NxK)^T ----------------
// 128x128 tile, BK=64, 4 waves; launch_bounds(256,3) caps VGPR at 170 so
// 3 blocks/CU are resident (gemm1's 768 blocks = exactly 3/CU, no tail).
template <int OUT_BF16>
__global__ __launch_bounds__(256, 3) void k_gemm_bt(
    const u16* __restrict__ A, const u16* __restrict__ Bt, void* __restrict__ Cv,
    int M, int N, int K) {
  __shared__ u16 smem[16384];  // As = [0:8192), Bs = [8192:16384)
  u16* As = smem;
  u16* Bs = smem + 8192;
  const int tid = threadIdx.x;
  const int wave = tid >> 6, lane = tid & 63;
  const int wr = wave >> 1, wc = wave & 1;
  const int quad = lane >> 4, fm = lane & 15;
  const int m0 = blockIdx.y * 128, n0 = blockIdx.x * 128;
  f32x4 acc[4][4];
  for (int i = 0; i < 4; ++i)
    for (int j = 0; j < 4; ++j)
      for (int r = 0; r < 4; ++r) acc[i][j][r] = 0.0f;

  const int lrow = lane >> 3;
  const int lcol = (lane & 7) * 8;
  const int fk = quad * 8;

  for (int kt = 0; kt < K; kt += 64) {
    for (int p = 0; p < 4; ++p) {
      int roff = wave * 32 + p * 8 + lrow;
      gl_lds16(A + (size_t)(m0 + roff) * K + kt + lcol,
               As + wave * 2048 + p * 512 + lane * 8);
      gl_lds16(Bt + (size_t)(n0 + roff) * K + kt + lcol,
               Bs + wave * 2048 + p * 512 + lane * 8);
    }
    __syncthreads();
    for (int s = 0; s < 2; ++s) {
      bf16x8 af[4], bfr[4];
      for (int i = 0; i < 4; ++i)
        af[i] = *(const bf16x8*)(As + (wr * 64 + i * 16 + fm) * 64 + s * 32 + fk);
      for (int j = 0; j < 4; ++j)
        bfr[j] = *(const bf16x8*)(Bs + (wc * 64 + j * 16 + fm) * 64 + s * 32 + fk);
      for (int i = 0; i < 4; ++i)
        for (int j = 0; j < 4; ++j)
          acc[i][j] = __builtin_amdgcn_mfma_f32_16x16x32_bf16(af[i], bfr[j],
                                                              acc[i][j], 0, 0, 0);
    }
    __syncthreads();
  }

  if (OUT_BF16) {
    // two half-tile passes: 64 rows x pitch 136 u16 = 17.4KB <= 32KB
    u16* Cs = smem;
    for (int hh = 0; hh < 2; ++hh) {
      if (hh) __syncthreads();
      if (wr == hh)
        for (int i = 0; i < 4; ++i)
          for (int j = 0; j < 4; ++j)
            for (int r = 0; r < 4; ++r)
              Cs[(i * 16 + quad * 4 + r) * 136 + wc * 64 + j * 16 + fm] =
                  f2bf(acc[i][j][r]);
      __syncthreads();
      for (int it = 0; it < 4; ++it) {
        int row = it * 16 + (tid >> 4);
        int col = (tid & 15) * 8;
        uint4 v = *(const uint4*)(Cs + row * 136 + col);
        *(uint4*)((u16*)Cv + (size_t)(m0 + hh * 64 + row) * N + n0 + col) = v;
      }
    }
  } else {
    // four quarter-tile passes: 32 rows x pitch 132 fp32 = 16.9KB <= 32KB
    float* Cf = (float*)smem;
    for (int p = 0; p < 4; ++p) {
      if (p) __syncthreads();
      if (wr == (p >> 1))
        for (int ii = 0; ii < 2; ++ii) {
          int i = 2 * (p & 1) + ii;
          for (int j = 0; j < 4; ++j)
            for (int r = 0; r < 4; ++r)
              Cf[(ii * 16 + quad * 4 + r) * 132 + wc * 64 + j * 16 + fm] =
                  acc[i][j][r];
        }
      __syncthreads();
      for (int it = 0; it < 4; ++it) {
        int row = it * 8 + (tid >> 5);
        int col = (tid & 31) * 4;
        float4 v = *(const float4*)(Cf + row * 132 + col);
        *(float4*)((float*)Cv + (size_t)(m0 + p * 32 + row) * N + n0 + col) = v;
      }
    }
  }
}

// ---------------- RMSnorm + RoPE + layout shuffle ----------------
// q gets 1/sqrt(D)*log2e folded in. V is written transposed (B,KV,D,L) with the
// key (l) index BIT-PERMUTED within 32-token groups so that the attention PV
// B-fragment (keys 32ks2+16(j>>2)+4quad+(j&3)) is one contiguous b128:
//   l = 32a+16b+4c+d  ->  lp = 32a+8c+4b+d
__global__ __launch_bounds__(256) void k_norm_rope(
    const u16* __restrict__ qkv, const float* __restrict__ cosp,
    const float* __restrict__ sinp, const float* __restrict__ qw,
    const float* __restrict__ kw, u16* __restrict__ Qb, u16* __restrict__ Kb,
    u16* __restrict__ Vtb) {
  int wid = blockIdx.x * 4 + (threadIdx.x >> 6);
  int lane = threadIdx.x & 63;
  int tok = wid / 24, unit = wid % 24;
  int b = tok >> 11, l = tok & 2047;
  const u16* row = qkv + (size_t)tok * 3072;
  int d0 = lane * 2;
  if (unit < 20) {
    int isq = unit < 16;
    int col = isq ? unit * 128 : 2048 + (unit - 16) * 128;
    u32 u = *(const u32*)(row + col + d0);
    float x0 = bf2f((u16)(u & 0xffff)), x1 = bf2f((u16)(u >> 16));
    float ss = x0 * x0 + x1 * x1;
    for (int m = 1; m < 64; m <<= 1) ss += __shfl_xor(ss, m);
    float rr = rsqrtf(ss * (1.0f / 128.0f) + 1e-6f);
    const float* wv = isq ? qw : kw;
    float n0 = x0 * rr * wv[d0], n1 = x1 * rr * wv[d0 + 1];
    float p0 = __shfl_xor(n0, 32), p1 = __shfl_xor(n1, 32);
    float sgn = (lane < 32) ? -1.0f : 1.0f;
    const float* cb = cosp + (size_t)tok * 128;
    const float* sb = sinp + (size_t)tok * 128;
    float o0 = n0 * cb[d0] + sgn * p0 * sb[d0];
    float o1 = n1 * cb[d0 + 1] + sgn * p1 * sb[d0 + 1];
    if (isq) {
      o0 *= QSCALE;
      o1 *= QSCALE;
      u32 packed = (u32)f2bf(o0) | ((u32)f2bf(o1) << 16);
      size_t off = (((size_t)(b * H_ + unit)) * L_ + l) * D_ + d0;
      *(u32*)(Qb + off) = packed;
    } else {
      u32 packed = (u32)f2bf(o0) | ((u32)f2bf(o1) << 16);
      size_t off = (((size_t)(b * KV_ + (unit - 16))) * L_ + l) * D_ + d0;
      *(u32*)(Kb + off) = packed;
    }
  } else {
    // v: transpose to (B,KV,D,L) with permuted l
    int g = unit - 20;
    int lp = (l & ~31) | (((l >> 2) & 3) << 3) | (((l >> 4) & 1) << 2) | (l & 3);
    size_t base = (((size_t)(b * KV_ + g)) * D_ + d0) * L_ + lp;
    Vtb[base] = row[2560 + g * 128 + d0];
    Vtb[base + L_] = row[2560 + g * 128 + d0 + 1];
  }
}

// ---------------- flash attention (S^T, fixed-max, 2 query-groups/wave) ----------------
// Q-block = 128: each wave owns 32 queries as two 16-wide B-operand groups.
// K-frags (A) and V-frags (B) are loaded from LDS ONCE and reused for both
// groups -> LDS bytes per query halved vs round 5 (the round-5 bottleneck).
__global__ __launch_bounds__(256, 2) void k_attn(const u16* __restrict__ Qb,
                                                 const u16* __restrict__ Kb,
                                                 const u16* __restrict__ Vtb,
                                                 u16* __restrict__ AO) {
  __shared__ u16 smem[16384];  // Ks 64x128 (8192), Vs 128x64 (8192)
  u16* Ks = smem;
  u16* Vs = smem + 8192;
  const int tid = threadIdx.x, wave = tid >> 6, lane = tid & 63;
  const int quad = lane >> 4, fm = lane & 15;
  const int f7 = fm & 7;
  const int qt = blockIdx.x, bh = blockIdx.y;
  const int b = bh >> 4, h = bh & 15, g = h >> 2;
  const u16* Kg = Kb + ((size_t)(b * KV_ + g)) * L_ * D_;
  const u16* Vg = Vtb + ((size_t)(b * KV_ + g)) * D_ * L_;

  // Q B-frags straight from global: group1 q = qt*128 + wave*32 + fm, group2 +16
  const u16* Qg = Qb + ((size_t)bh * L_ + qt * 128 + wave * 32 + fm) * D_;
  bf16x8 qf1[4], qf2[4];
  for (int ks = 0; ks < 4; ++ks) {
    qf1[ks] = *(const bf16x8*)(Qg + ks * 32 + quad * 8);
    qf2[ks] = *(const bf16x8*)(Qg + 16 * D_ + ks * 32 + quad * 8);
  }

  f32x4 o1[8], o2[8];  // O frag f: col d=f*16+fm, row q=quad*4+r (per group)
  for (int f = 0; f < 8; ++f)
    for (int r = 0; r < 4; ++r) { o1[f][r] = 0.0f; o2[f][r] = 0.0f; }
  float lr1 = 0.0f, lr2 = 0.0f;  // per-lane denominators for q = fm (per group)

  const int eK = wave * 2048 + (lane << 3);
  const int cK = lane & 15;
  const int cV = lane & 7;
  for (int kt = 0; kt < 32; ++kt) {
    __syncthreads();
    for (int p = 0; p < 4; ++p) {
      int e = eK + p * 512;
      int rowK = e >> 7;
      int gK = (cK & 8) | ((cK & 7) ^ (rowK & 7));
      gl_lds16(Kg + (size_t)(kt * 64 + rowK) * 128 + gK * 8, Ks + e);
      int rowV = e >> 6;
      int gV = cV ^ (rowV & 7);
      gl_lds16(Vg + (size_t)rowV * L_ + kt * 64 + gV * 8, Vs + e);
    }
    __syncthreads();

    // S^T = K Q^T : each kf load feeds both query groups
    f32x4 s1[4], s2[4];
    for (int n = 0; n < 4; ++n)
      for (int r = 0; r < 4; ++r) { s1[n][r] = 0.0f; s2[n][r] = 0.0f; }
    for (int ks = 0; ks < 4; ++ks) {
      int c = 4 * ks + quad;
      int cp = (c & 8) | ((c & 7) ^ f7);
      for (int n = 0; n < 4; ++n) {
        bf16x8 kf = *(const bf16x8*)(Ks + (n * 16 + fm) * 128 + cp * 8);
        s1[n] = __builtin_amdgcn_mfma_f32_16x16x32_bf16(kf, qf1[ks], s1[n], 0, 0, 0);
        s2[n] = __builtin_amdgcn_mfma_f32_16x16x32_bf16(kf, qf2[ks], s2[n], 0, 0, 0);
      }
    }

    // fixed-max softmax: P = exp2(s - SMAX), no reductions in the loop
    u32 pk1[4][2], pk2[4][2];
    float rs1 = 0.0f, rs2 = 0.0f;
    for (int n = 0; n < 4; ++n) {
      float a0 = __builtin_amdgcn_exp2f(s1[n][0] - SMAX);
      float a1 = __builtin_amdgcn_exp2f(s1[n][1] - SMAX);
      float a2 = __builtin_amdgcn_exp2f(s1[n][2] - SMAX);
      float a3 = __builtin_amdgcn_exp2f(s1[n][3] - SMAX);
      rs1 += (a0 + a1) + (a2 + a3);
      pk1[n][0] = pkbf(a0, a1);
      pk1[n][1] = pkbf(a2, a3);
      float b0 = __builtin_amdgcn_exp2f(s2[n][0] - SMAX);
      float b1 = __builtin_amdgcn_exp2f(s2[n][1] - SMAX);
      float b2 = __builtin_amdgcn_exp2f(s2[n][2] - SMAX);
      float b3 = __builtin_amdgcn_exp2f(s2[n][3] - SMAX);
      rs2 += (b0 + b1) + (b2 + b3);
      pk2[n][0] = pkbf(b0, b1);
      pk2[n][1] = pkbf(b2, b3);
    }
    lr1 += rs1;
    lr2 += rs2;

    // O += P V via K=32 bf16: each vv load feeds both groups
    for (int ks2 = 0; ks2 < 2; ++ks2) {
      union { u32 u[4]; bf16x8 v; } pa1, pa2;
      pa1.u[0] = pk1[2 * ks2][0];
      pa1.u[1] = pk1[2 * ks2][1];
      pa1.u[2] = pk1[2 * ks2 + 1][0];
      pa1.u[3] = pk1[2 * ks2 + 1][1];
      pa2.u[0] = pk2[2 * ks2][0];
      pa2.u[1] = pk2[2 * ks2][1];
      pa2.u[2] = pk2[2 * ks2 + 1][0];
      pa2.u[3] = pk2[2 * ks2 + 1][1];
      int chunk = (4 * ks2 + quad) ^ f7;
      for (int f = 0; f < 8; ++f) {
        bf16x8 vv = *(const bf16x8*)(Vs + (f * 16 + fm) * 64 + chunk * 8);
        o1[f] = __builtin_amdgcn_mfma_f32_16x16x32_bf16(pa1.v, vv, o1[f], 0, 0, 0);
        o2[f] = __builtin_amdgcn_mfma_f32_16x16x32_bf16(pa2.v, vv, o2[f], 0, 0, 0);
      }
    }
  }

  // epilogue: two passes (group1 rows q=wave*32+quad*4+r, group2 +16)
  const size_t tok0 = (size_t)b * L_ + qt * 128;
  for (int grp = 0; grp < 2; ++grp) {
    f32x4* o = grp ? o2 : o1;
    float lr = grp ? lr2 : lr1;
    lr += __shfl_xor(lr, 16);
    lr += __shfl_xor(lr, 32);
    float li = 1.0f / lr;
    float l0 = __shfl(li, (lane & 48) | (quad * 4 + 0));
    float l1 = __shfl(li, (lane & 48) | (quad * 4 + 1));
    float l2 = __shfl(li, (lane & 48) | (quad * 4 + 2));
    float l3 = __shfl(li, (lane & 48) | (quad * 4 + 3));
    __syncthreads();
    for (int f = 0; f < 8; ++f) {
      int e = (wave * 16 + quad * 4) * 136 + f * 16 + fm;
      smem[e] = f2bf(o[f][0] * l0);
      smem[e + 136] = f2bf(o[f][1] * l1);
      smem[e + 272] = f2bf(o[f][2] * l2);
      smem[e + 408] = f2bf(o[f][3] * l3);
    }
    __syncthreads();
    for (int it = 0; it < 8; ++it) {
      int crow = (tid >> 6) * 16 + it * 2 + (lane >> 5);   // compact row 0..63
      int q = (crow >> 4) * 32 + grp * 16 + (crow & 15);   // global q in block
      int cc = (lane & 31) * 4;
      uint2 v = *(const uint2*)(smem + crow * 136 + cc);
      *(uint2*)(AO + (tok0 + q) * (H_ * D_) + h * D_ + cc) = v;
    }
  }
}

// ---------------- launcher ----------------
extern "C" void kernel_launch(void* const* d_in, const int* in_sizes, int n_in,
                              void* d_out, int out_size, void* d_ws,
                              size_t ws_size, hipStream_t stream) {
  const float* hidden = (const float*)d_in[0];
  const float* cosp = (const float*)d_in[1];
  const float* sinp = (const float*)d_in[2];
  const float* Wq = (const float*)d_in[3];
  const float* Wk = (const float*)d_in[4];
  const float* Wv = (const float*)d_in[5];
  const float* Wo = (const float*)d_in[6];
  const float* qw = (const float*)d_in[7];
  const float* kw = (const float*)d_in[8];
  float* out = (float*)d_out;

  char* w = (char*)d_ws;
  u16* Xb = (u16*)(w);                          // 4096x2048 bf16, 16MB
  u16* Wtqkv = (u16*)(w + (16u << 20));         // 3072x2048 bf16, 12MB
  u16* Wto = (u16*)(w + (28u << 20));           // 2048x2048 bf16, 8MB
  u16* qkv = (u16*)(w + (36u << 20));           // 4096x3072 bf16, 24MB
  u16* Qb = (u16*)(w + (60u << 20));            // 16MB
  u16* Kb = (u16*)(w + (76u << 20));            // 4MB
  u16* Vtb = (u16*)(w + (80u << 20));           // 4MB bf16 (ends 84MB)
  u16* AO = Xb;                                 // reuse after GEMM1

  k_f2b<<<8192, 256, 0, stream>>>(hidden, Xb, 2097152);
  k_tconv_all<<<10240, dim3(32, 8), 0, stream>>>(Wq, Wk, Wv, Wo, Wtqkv, Wto);
  k_gemm_bt<1><<<dim3(24, 32), 256, 0, stream>>>(Xb, Wtqkv, qkv, 4096, 3072, 2048);
  k_norm_rope<<<24576, 256, 0, stream>>>(qkv, cosp, sinp, qw, kw, Qb, Kb, Vtb);
  k_attn<<<dim3(16, 32), 256, 0, stream>>>(Qb, Kb, Vtb, AO);
  k_gemm_bt<0><<<dim3(16, 32), 256, 0, stream>>>(AO, Wto, out, 4096, 2048, 2048);
}

// Round 8
// 336.963 us; speedup vs baseline: 1.2520x; 1.0083x over previous
//
#include <hip/hip_runtime.h>

typedef unsigned short u16;
typedef unsigned int u32;
typedef short bf16x8 __attribute__((ext_vector_type(8)));
typedef float f32x4 __attribute__((ext_vector_type(4)));

#define B_ 2
#define L_ 2048
#define H_ 16
#define KV_ 4
#define D_ 128
#define HID_ 2048

// 1/sqrt(128) * log2(e): folded into Q so softmax runs in exp2 domain
#define QSCALE (0.08838834764831845f * 1.4426950408889634f)
// fixed softmax max: |s| <= 128*scale*log2e = 16.34 (Cauchy-Schwarz on rms-normed q,k)
#define SMAX 17.0f

__device__ __forceinline__ u16 f2bf(float f) {
  union { float f; u32 u; } v; v.f = f;
  u32 u = v.u;
  return (u16)((u + 0x7FFFu + ((u >> 16) & 1u)) >> 16);
}
__device__ __forceinline__ float bf2f(u16 h) {
  union { u32 u; float f; } v; v.u = ((u32)h) << 16;
  return v.f;
}
// pack two floats to bf16 pair (round-half-up; inputs are P in [0,1], no NaN/ovf)
__device__ __forceinline__ u32 pkbf(float a, float b) {
  union { float f; u32 u; } x, y; x.f = a; y.f = b;
  return ((x.u + 0x8000u) >> 16) | ((y.u + 0x8000u) & 0xffff0000u);
}
__device__ __forceinline__ void gl_lds16(const void* g, void* l) {
  __builtin_amdgcn_global_load_lds((__attribute__((address_space(1))) void*)(g),
                                   (__attribute__((address_space(3))) void*)(l),
                                   16, 0, 0);
}

// ---------------- prep: fp32->bf16 X convert + all weight transposes ----------------
// blocks [0,8192): f2b of hidden (8192*256 float4 = exactly 2M float4)
// blocks [8192,18432): 32x32 transpose tiles of Wq/Wk/Wv/Wo
__global__ void k_prep(const float* __restrict__ hidden, u16* __restrict__ Xb,
                       const float* __restrict__ Wq, const float* __restrict__ Wk,
                       const float* __restrict__ Wv, const float* __restrict__ Wo,
                       u16* __restrict__ Wtqkv, u16* __restrict__ Wto) {
  __shared__ float t[32][33];
  int id = blockIdx.x;
  if (id < 8192) {
    int i = id * 256 + threadIdx.x;
    float4 v = ((const float4*)hidden)[i];
    u32 a = (u32)f2bf(v.x) | ((u32)f2bf(v.y) << 16);
    u32 b = (u32)f2bf(v.z) | ((u32)f2bf(v.w) << 16);
    ((uint2*)Xb)[i] = make_uint2(a, b);
    return;
  }
  id -= 8192;
  const float* src; u16* dst; int C; int ct, rt;
  if (id < 4096)      { src = Wq; dst = Wtqkv;               C = 2048; ct = id & 63; rt = id >> 6; }
  else if (id < 5120) { id -= 4096; src = Wk; dst = Wtqkv + 2048 * 2048; C = 512; ct = id & 15; rt = id >> 4; }
  else if (id < 6144) { id -= 5120; src = Wv; dst = Wtqkv + 2560 * 2048; C = 512; ct = id & 15; rt = id >> 4; }
  else                { id -= 6144; src = Wo; dst = Wto;     C = 2048; ct = id & 63; rt = id >> 6; }
  const int R = 2048;
  int c0 = ct * 32, r0 = rt * 32;
  int tx = threadIdx.x & 31, ty = threadIdx.x >> 5;
  for (int i = ty; i < 32; i += 8)
    t[i][tx] = src[(size_t)(r0 + i) * C + c0 + tx];
  __syncthreads();
  for (int i = ty; i < 32; i += 8)
    dst[(size_t)(c0 + i) * R + r0 + tx] = f2bf(t[tx][i]);
}

// ---------------- bf16 GEMM: C(MxN) = A(MxK) @ Bt(NxK)^T ----------------
// 128x128 tile, BK=64, 4 waves; launch_bounds(256,3) -> 3 blocks/CU resident.
template <int OUT_BF16>
__global__ __launch_bounds__(256, 3) void k_gemm_bt(
    const u16* __restrict__ A, const u16* __restrict__ Bt, void* __restrict__ Cv,
    int M, int N, int K) {
  __shared__ u16 smem[16384];  // As = [0:8192), Bs = [8192:16384)
  u16* As = smem;
  u16* Bs = smem + 8192;
  const int tid = threadIdx.x;
  const int wave = tid >> 6, lane = tid & 63;
  const int wr = wave >> 1, wc = wave & 1;
  const int quad = lane >> 4, fm = lane & 15;
  const int m0 = blockIdx.y * 128, n0 = blockIdx.x * 128;
  f32x4 acc[4][4];
  for (int i = 0; i < 4; ++i)
    for (int j = 0; j < 4; ++j)
      for (int r = 0; r < 4; ++r) acc[i][j][r] = 0.0f;

  const int lrow = lane >> 3;
  const int lcol = (lane & 7) * 8;
  const int fk = quad * 8;

  for (int kt = 0; kt < K; kt += 64) {
    for (int p = 0; p < 4; ++p) {
      int roff = wave * 32 + p * 8 + lrow;
      gl_lds16(A + (size_t)(m0 + roff) * K + kt + lcol,
               As + wave * 2048 + p * 512 + lane * 8);
      gl_lds16(Bt + (size_t)(n0 + roff) * K + kt + lcol,
               Bs + wave * 2048 + p * 512 + lane * 8);
    }
    __syncthreads();
    for (int s = 0; s < 2; ++s) {
      bf16x8 af[4], bfr[4];
      for (int i = 0; i < 4; ++i)
        af[i] = *(const bf16x8*)(As + (wr * 64 + i * 16 + fm) * 64 + s * 32 + fk);
      for (int j = 0; j < 4; ++j)
        bfr[j] = *(const bf16x8*)(Bs + (wc * 64 + j * 16 + fm) * 64 + s * 32 + fk);
      for (int i = 0; i < 4; ++i)
        for (int j = 0; j < 4; ++j)
          acc[i][j] = __builtin_amdgcn_mfma_f32_16x16x32_bf16(af[i], bfr[j],
                                                              acc[i][j], 0, 0, 0);
    }
    __syncthreads();
  }

  if (OUT_BF16) {
    u16* Cs = smem;
    for (int hh = 0; hh < 2; ++hh) {
      if (hh) __syncthreads();
      if (wr == hh)
        for (int i = 0; i < 4; ++i)
          for (int j = 0; j < 4; ++j)
            for (int r = 0; r < 4; ++r)
              Cs[(i * 16 + quad * 4 + r) * 136 + wc * 64 + j * 16 + fm] =
                  f2bf(acc[i][j][r]);
      __syncthreads();
      for (int it = 0; it < 4; ++it) {
        int row = it * 16 + (tid >> 4);
        int col = (tid & 15) * 8;
        uint4 v = *(const uint4*)(Cs + row * 136 + col);
        *(uint4*)((u16*)Cv + (size_t)(m0 + hh * 64 + row) * N + n0 + col) = v;
      }
    }
  } else {
    float* Cf = (float*)smem;
    for (int p = 0; p < 4; ++p) {
      if (p) __syncthreads();
      if (wr == (p >> 1))
        for (int ii = 0; ii < 2; ++ii) {
          int i = 2 * (p & 1) + ii;
          for (int j = 0; j < 4; ++j)
            for (int r = 0; r < 4; ++r)
              Cf[(ii * 16 + quad * 4 + r) * 132 + wc * 64 + j * 16 + fm] =
                  acc[i][j][r];
        }
      __syncthreads();
      for (int it = 0; it < 4; ++it) {
        int row = it * 8 + (tid >> 5);
        int col = (tid & 31) * 4;
        float4 v = *(const float4*)(Cf + row * 132 + col);
        *(float4*)((float*)Cv + (size_t)(m0 + p * 32 + row) * N + n0 + col) = v;
      }
    }
  }
}

// ---------------- RMSnorm + RoPE (q/k heads only; V handled by k_vtrans) ----------------
__global__ __launch_bounds__(256) void k_norm_rope(
    const u16* __restrict__ qkv, const float* __restrict__ cosp,
    const float* __restrict__ sinp, const float* __restrict__ qw,
    const float* __restrict__ kw, u16* __restrict__ Qb, u16* __restrict__ Kb) {
  int wid = blockIdx.x * 4 + (threadIdx.x >> 6);
  int lane = threadIdx.x & 63;
  int tok = wid / 20, unit = wid % 20;
  int b = tok >> 11, l = tok & 2047;
  const u16* row = qkv + (size_t)tok * 3072;
  int d0 = lane * 2;
  int isq = unit < 16;
  int col = isq ? unit * 128 : 2048 + (unit - 16) * 128;
  u32 u = *(const u32*)(row + col + d0);
  float x0 = bf2f((u16)(u & 0xffff)), x1 = bf2f((u16)(u >> 16));
  float ss = x0 * x0 + x1 * x1;
  for (int m = 1; m < 64; m <<= 1) ss += __shfl_xor(ss, m);
  float rr = rsqrtf(ss * (1.0f / 128.0f) + 1e-6f);
  const float* wv = isq ? qw : kw;
  float n0 = x0 * rr * wv[d0], n1 = x1 * rr * wv[d0 + 1];
  float p0 = __shfl_xor(n0, 32), p1 = __shfl_xor(n1, 32);
  float sgn = (lane < 32) ? -1.0f : 1.0f;
  const float* cb = cosp + (size_t)tok * 128;
  const float* sb = sinp + (size_t)tok * 128;
  float o0 = n0 * cb[d0] + sgn * p0 * sb[d0];
  float o1 = n1 * cb[d0 + 1] + sgn * p1 * sb[d0 + 1];
  if (isq) {
    o0 *= QSCALE;
    o1 *= QSCALE;
    u32 packed = (u32)f2bf(o0) | ((u32)f2bf(o1) << 16);
    size_t off = (((size_t)(b * H_ + unit)) * L_ + l) * D_ + d0;
    *(u32*)(Qb + off) = packed;
  } else {
    u32 packed = (u32)f2bf(o0) | ((u32)f2bf(o1) << 16);
    size_t off = (((size_t)(b * KV_ + (unit - 16))) * L_ + l) * D_ + d0;
    *(u32*)(Kb + off) = packed;
  }
}

// ---------------- V transpose to (B,KV,D,L) with permuted l, coalesced ----------------
// perm within 32-token groups: l = 16b2+4c+d2 -> lp = 8c+4b2+d2
// so the attention PV B-frag is one contiguous b128 in the Vt tile.
__global__ __launch_bounds__(256) void k_vtrans(const u16* __restrict__ qkv,
                                                u16* __restrict__ Vtb) {
  __shared__ u16 t[64][136];  // [l_local][d], pitch 136 u16 = 272B (16B aligned)
  int blk = blockIdx.x;  // 256 blocks: (b, g, lt)
  int lt = blk & 31, g = (blk >> 5) & 3, b = blk >> 7;
  int l0 = lt * 64;
  for (int p = 0; p < 4; ++p) {
    int idx = p * 256 + threadIdx.x;          // 0..1023
    int r = idx >> 4, co = (idx & 15) * 8;    // row 0..63, col chunk of 8 u16
    uint4 v = *(const uint4*)(qkv + (size_t)(b * 2048 + l0 + r) * 3072 + 2560 +
                              g * 128 + co);
    *(uint4*)(&t[r][co]) = v;
  }
  __syncthreads();
  int d = threadIdx.x >> 1, lh = threadIdx.x & 1;
  u16* dst = Vtb + (((size_t)(b * KV_ + g)) * D_ + d) * L_ + l0 + lh * 32;
  for (int bc = 0; bc < 8; ++bc) {
    int bb = bc & 1, c = bc >> 1;
    int ls = lh * 32 + 16 * bb + 4 * c;
    u32 lo = (u32)t[ls][d] | ((u32)t[ls + 1][d] << 16);
    u32 hi = (u32)t[ls + 2][d] | ((u32)t[ls + 3][d] << 16);
    *(uint2*)(dst + 8 * c + 4 * bb) = make_uint2(lo, hi);
  }
}

// ---------------- flash attention (S^T, fixed-max, 2 groups/wave, LDS dbuf) ----------------
// Double-buffered K/V staging: tile kt+1 is prefetched into the other 32KB
// buffer right after the barrier that publishes tile kt, overlapping HBM
// latency with compute. One barrier per tile.
__global__ __launch_bounds__(256, 2) void k_attn(const u16* __restrict__ Qb,
                                                 const u16* __restrict__ Kb,
                                                 const u16* __restrict__ Vtb,
                                                 u16* __restrict__ AO) {
  __shared__ u16 smem[32768];  // buf0: Ks 64x128 + Vs 128x64 (32KB), buf1: +16384
  const int tid = threadIdx.x, wave = tid >> 6, lane = tid & 63;
  const int quad = lane >> 4, fm = lane & 15;
  const int f7 = fm & 7;
  const int qt = blockIdx.x, bh = blockIdx.y;
  const int b = bh >> 4, h = bh & 15, g = h >> 2;
  const u16* Kg = Kb + ((size_t)(b * KV_ + g)) * L_ * D_;
  const u16* Vg = Vtb + ((size_t)(b * KV_ + g)) * D_ * L_;

  const u16* Qg = Qb + ((size_t)bh * L_ + qt * 128 + wave * 32 + fm) * D_;
  bf16x8 qf1[4], qf2[4];
  for (int ks = 0; ks < 4; ++ks) {
    qf1[ks] = *(const bf16x8*)(Qg + ks * 32 + quad * 8);
    qf2[ks] = *(const bf16x8*)(Qg + 16 * D_ + ks * 32 + quad * 8);
  }

  f32x4 o1[8], o2[8];
  for (int f = 0; f < 8; ++f)
    for (int r = 0; r < 4; ++r) { o1[f][r] = 0.0f; o2[f][r] = 0.0f; }
  float lr1 = 0.0f, lr2 = 0.0f;

  const int eK = wave * 2048 + (lane << 3);
  const int cK = lane & 15;
  const int cV = lane & 7;

#define STAGE(kt_, buf_)                                                      \
  {                                                                           \
    u16* Kd = smem + (buf_)*16384;                                            \
    u16* Vd = smem + (buf_)*16384 + 8192;                                     \
    for (int p = 0; p < 4; ++p) {                                             \
      int e = eK + p * 512;                                                   \
      int rowK = e >> 7;                                                      \
      int gK = (cK & 8) | ((cK & 7) ^ (rowK & 7));                            \
      gl_lds16(Kg + (size_t)((kt_)*64 + rowK) * 128 + gK * 8, Kd + e);        \
      int rowV = e >> 6;                                                      \
      int gV = cV ^ (rowV & 7);                                               \
      gl_lds16(Vg + (size_t)rowV * L_ + (kt_)*64 + gV * 8, Vd + e);           \
    }                                                                         \
  }

  STAGE(0, 0);
  for (int kt = 0; kt < 32; ++kt) {
    __syncthreads();  // drains vmcnt: tile kt (staged last iter) is now visible
    if (kt + 1 < 32) STAGE(kt + 1, (kt + 1) & 1);  // prefetch into other buffer
    const u16* Ks = smem + (kt & 1) * 16384;
    const u16* Vs = Ks + 8192;

    // S^T = K Q^T : each kf load feeds both query groups
    f32x4 s1[4], s2[4];
    for (int n = 0; n < 4; ++n)
      for (int r = 0; r < 4; ++r) { s1[n][r] = 0.0f; s2[n][r] = 0.0f; }
    for (int ks = 0; ks < 4; ++ks) {
      int c = 4 * ks + quad;
      int cp = (c & 8) | ((c & 7) ^ f7);
      for (int n = 0; n < 4; ++n) {
        bf16x8 kf = *(const bf16x8*)(Ks + (n * 16 + fm) * 128 + cp * 8);
        s1[n] = __builtin_amdgcn_mfma_f32_16x16x32_bf16(kf, qf1[ks], s1[n], 0, 0, 0);
        s2[n] = __builtin_amdgcn_mfma_f32_16x16x32_bf16(kf, qf2[ks], s2[n], 0, 0, 0);
      }
    }

    // fixed-max softmax
    u32 pk1[4][2], pk2[4][2];
    float rs1 = 0.0f, rs2 = 0.0f;
    for (int n = 0; n < 4; ++n) {
      float a0 = __builtin_amdgcn_exp2f(s1[n][0] - SMAX);
      float a1 = __builtin_amdgcn_exp2f(s1[n][1] - SMAX);
      float a2 = __builtin_amdgcn_exp2f(s1[n][2] - SMAX);
      float a3 = __builtin_amdgcn_exp2f(s1[n][3] - SMAX);
      rs1 += (a0 + a1) + (a2 + a3);
      pk1[n][0] = pkbf(a0, a1);
      pk1[n][1] = pkbf(a2, a3);
      float b0 = __builtin_amdgcn_exp2f(s2[n][0] - SMAX);
      float b1 = __builtin_amdgcn_exp2f(s2[n][1] - SMAX);
      float b2 = __builtin_amdgcn_exp2f(s2[n][2] - SMAX);
      float b3 = __builtin_amdgcn_exp2f(s2[n][3] - SMAX);
      rs2 += (b0 + b1) + (b2 + b3);
      pk2[n][0] = pkbf(b0, b1);
      pk2[n][1] = pkbf(b2, b3);
    }
    lr1 += rs1;
    lr2 += rs2;

    // O += P V via K=32 bf16: each vv load feeds both groups
    for (int ks2 = 0; ks2 < 2; ++ks2) {
      union { u32 u[4]; bf16x8 v; } pa1, pa2;
      pa1.u[0] = pk1[2 * ks2][0];
      pa1.u[1] = pk1[2 * ks2][1];
      pa1.u[2] = pk1[2 * ks2 + 1][0];
      pa1.u[3] = pk1[2 * ks2 + 1][1];
      pa2.u[0] = pk2[2 * ks2][0];
      pa2.u[1] = pk2[2 * ks2][1];
      pa2.u[2] = pk2[2 * ks2 + 1][0];
      pa2.u[3] = pk2[2 * ks2 + 1][1];
      int chunk = (4 * ks2 + quad) ^ f7;
      for (int f = 0; f < 8; ++f) {
        bf16x8 vv = *(const bf16x8*)(Vs + (f * 16 + fm) * 64 + chunk * 8);
        o1[f] = __builtin_amdgcn_mfma_f32_16x16x32_bf16(pa1.v, vv, o1[f], 0, 0, 0);
        o2[f] = __builtin_amdgcn_mfma_f32_16x16x32_bf16(pa2.v, vv, o2[f], 0, 0, 0);
      }
    }
  }
#undef STAGE

  // epilogue: two passes (group1 rows q=wave*32+quad*4+r, group2 +16)
  const size_t tok0 = (size_t)b * L_ + qt * 128;
  for (int grp = 0; grp < 2; ++grp) {
    f32x4* o = grp ? o2 : o1;
    float lr = grp ? lr2 : lr1;
    lr += __shfl_xor(lr, 16);
    lr += __shfl_xor(lr, 32);
    float li = 1.0f / lr;
    float l0 = __shfl(li, (lane & 48) | (quad * 4 + 0));
    float l1 = __shfl(li, (lane & 48) | (quad * 4 + 1));
    float l2 = __shfl(li, (lane & 48) | (quad * 4 + 2));
    float l3 = __shfl(li, (lane & 48) | (quad * 4 + 3));
    __syncthreads();
    for (int f = 0; f < 8; ++f) {
      int e = (wave * 16 + quad * 4) * 136 + f * 16 + fm;
      smem[e] = f2bf(o[f][0] * l0);
      smem[e + 136] = f2bf(o[f][1] * l1);
      smem[e + 272] = f2bf(o[f][2] * l2);
      smem[e + 408] = f2bf(o[f][3] * l3);
    }
    __syncthreads();
    for (int it = 0; it < 8; ++it) {
      int crow = (tid >> 6) * 16 + it * 2 + (lane >> 5);
      int q = (crow >> 4) * 32 + grp * 16 + (crow & 15);
      int cc = (lane & 31) * 4;
      uint2 v = *(const uint2*)(smem + crow * 136 + cc);
      *(uint2*)(AO + (tok0 + q) * (H_ * D_) + h * D_ + cc) = v;
    }
  }
}

// ---------------- launcher ----------------
extern "C" void kernel_launch(void* const* d_in, const int* in_sizes, int n_in,
                              void* d_out, int out_size, void* d_ws,
                              size_t ws_size, hipStream_t stream) {
  const float* hidden = (const float*)d_in[0];
  const float* cosp = (const float*)d_in[1];
  const float* sinp = (const float*)d_in[2];
  const float* Wq = (const float*)d_in[3];
  const float* Wk = (const float*)d_in[4];
  const float* Wv = (const float*)d_in[5];
  const float* Wo = (const float*)d_in[6];
  const float* qw = (const float*)d_in[7];
  const float* kw = (const float*)d_in[8];
  float* out = (float*)d_out;

  char* w = (char*)d_ws;
  u16* Xb = (u16*)(w);                          // 4096x2048 bf16, 16MB
  u16* Wtqkv = (u16*)(w + (16u << 20));         // 3072x2048 bf16, 12MB
  u16* Wto = (u16*)(w + (28u << 20));           // 2048x2048 bf16, 8MB
  u16* qkv = (u16*)(w + (36u << 20));           // 4096x3072 bf16, 24MB
  u16* Qb = (u16*)(w + (60u << 20));            // 16MB
  u16* Kb = (u16*)(w + (76u << 20));            // 4MB
  u16* Vtb = (u16*)(w + (80u << 20));           // 4MB bf16 (ends 84MB)
  u16* AO = Xb;                                 // reuse after GEMM1

  k_prep<<<18432, 256, 0, stream>>>(hidden, Xb, Wq, Wk, Wv, Wo, Wtqkv, Wto);
  k_gemm_bt<1><<<dim3(24, 32), 256, 0, stream>>>(Xb, Wtqkv, qkv, 4096, 3072, 2048);
  k_norm_rope<<<20480, 256, 0, stream>>>(qkv, cosp, sinp, qw, kw, Qb, Kb);
  k_vtrans<<<256, 256, 0, stream>>>(qkv, Vtb);
  k_attn<<<dim3(16, 32), 256, 0, stream>>>(Qb, Kb, Vtb, AO);
  k_gemm_bt<0><<<dim3(16, 32), 256, 0, stream>>>(AO, Wto, out, 4096, 2048, 2048);
}

// Round 9
// 325.320 us; speedup vs baseline: 1.2968x; 1.0358x over previous
//
#include <hip/hip_runtime.h>

typedef unsigned short u16;
typedef unsigned int u32;
typedef short bf16x8 __attribute__((ext_vector_type(8)));
typedef float f32x4 __attribute__((ext_vector_type(4)));

#define B_ 2
#define L_ 2048
#define H_ 16
#define KV_ 4
#define D_ 128
#define HID_ 2048

// 1/sqrt(128) * log2(e): folded into Q so softmax runs in exp2 domain.
// |s| <= 128*scale*log2e = 16.34 (Cauchy-Schwarz on rms-normed q,k), so
// 2^s <= ~9e4: no overflow anywhere and the scale cancels in O/lr -> no SMAX.
#define QSCALE (0.08838834764831845f * 1.4426950408889634f)

__device__ __forceinline__ u16 f2bf(float f) {
  union { float f; u32 u; } v; v.f = f;
  u32 u = v.u;
  return (u16)((u + 0x7FFFu + ((u >> 16) & 1u)) >> 16);
}
__device__ __forceinline__ float bf2f(u16 h) {
  union { u32 u; float f; } v; v.u = ((u32)h) << 16;
  return v.f;
}
// pack two floats to bf16 pair (round-half-up; inputs are P >= 0, no NaN/ovf)
__device__ __forceinline__ u32 pkbf(float a, float b) {
  union { float f; u32 u; } x, y; x.f = a; y.f = b;
  return ((x.u + 0x8000u) >> 16) | ((y.u + 0x8000u) & 0xffff0000u);
}
__device__ __forceinline__ void gl_lds16(const void* g, void* l) {
  __builtin_amdgcn_global_load_lds((__attribute__((address_space(1))) void*)(g),
                                   (__attribute__((address_space(3))) void*)(l),
                                   16, 0, 0);
}

// ---------------- prep: fp32->bf16 X convert + all weight transposes ----------------
__global__ void k_prep(const float* __restrict__ hidden, u16* __restrict__ Xb,
                       const float* __restrict__ Wq, const float* __restrict__ Wk,
                       const float* __restrict__ Wv, const float* __restrict__ Wo,
                       u16* __restrict__ Wtqkv, u16* __restrict__ Wto) {
  __shared__ float t[32][33];
  int id = blockIdx.x;
  if (id < 8192) {
    int i = id * 256 + threadIdx.x;
    float4 v = ((const float4*)hidden)[i];
    u32 a = (u32)f2bf(v.x) | ((u32)f2bf(v.y) << 16);
    u32 b = (u32)f2bf(v.z) | ((u32)f2bf(v.w) << 16);
    ((uint2*)Xb)[i] = make_uint2(a, b);
    return;
  }
  id -= 8192;
  const float* src; u16* dst; int C; int ct, rt;
  if (id < 4096)      { src = Wq; dst = Wtqkv;               C = 2048; ct = id & 63; rt = id >> 6; }
  else if (id < 5120) { id -= 4096; src = Wk; dst = Wtqkv + 2048 * 2048; C = 512; ct = id & 15; rt = id >> 4; }
  else if (id < 6144) { id -= 5120; src = Wv; dst = Wtqkv + 2560 * 2048; C = 512; ct = id & 15; rt = id >> 4; }
  else                { id -= 6144; src = Wo; dst = Wto;     C = 2048; ct = id & 63; rt = id >> 6; }
  const int R = 2048;
  int c0 = ct * 32, r0 = rt * 32;
  int tx = threadIdx.x & 31, ty = threadIdx.x >> 5;
  for (int i = ty; i < 32; i += 8)
    t[i][tx] = src[(size_t)(r0 + i) * C + c0 + tx];
  __syncthreads();
  for (int i = ty; i < 32; i += 8)
    dst[(size_t)(c0 + i) * R + r0 + tx] = f2bf(t[tx][i]);
}

// ---------------- fused QKV GEMM + RMSnorm + RoPE + V-transpose ----------------
// C(4096x3072) = Xb @ Wtqkv^T. Each 128x128 output tile is exactly one head
// slice (head = blockIdx.x: 0-15 q, 16-19 k, 20-23 v) x 128 tokens, so the
// norm/rope/vtrans epilogue runs straight from the LDS-staged tile. The qkv
// intermediate buffer is eliminated entirely.
__global__ __launch_bounds__(256, 3) void k_gemm_qkv(
    const u16* __restrict__ A, const u16* __restrict__ Bt,
    const float* __restrict__ cosp, const float* __restrict__ sinp,
    const float* __restrict__ qw, const float* __restrict__ kw,
    u16* __restrict__ Qb, u16* __restrict__ Kb, u16* __restrict__ Vtb) {
  __shared__ u16 smem[24576];  // As 8192 | Bs 8192 ; epilogue reuses as Cs 128x136
  u16* As = smem;
  u16* Bs = smem + 8192;
  const int tid = threadIdx.x;
  const int wave = tid >> 6, lane = tid & 63;
  const int wr = wave >> 1, wc = wave & 1;
  const int quad = lane >> 4, fm = lane & 15;
  const int K = 2048;
  const int m0 = blockIdx.y * 128, n0 = blockIdx.x * 128;
  f32x4 acc[4][4];
  for (int i = 0; i < 4; ++i)
    for (int j = 0; j < 4; ++j)
      for (int r = 0; r < 4; ++r) acc[i][j][r] = 0.0f;

  const int lrow = lane >> 3;
  const int lcol = (lane & 7) * 8;
  const int fk = quad * 8;

  for (int kt = 0; kt < K; kt += 64) {
    for (int p = 0; p < 4; ++p) {
      int roff = wave * 32 + p * 8 + lrow;
      gl_lds16(A + (size_t)(m0 + roff) * K + kt + lcol,
               As + wave * 2048 + p * 512 + lane * 8);
      gl_lds16(Bt + (size_t)(n0 + roff) * K + kt + lcol,
               Bs + wave * 2048 + p * 512 + lane * 8);
    }
    __syncthreads();
    for (int s = 0; s < 2; ++s) {
      bf16x8 af[4], bfr[4];
      for (int i = 0; i < 4; ++i)
        af[i] = *(const bf16x8*)(As + (wr * 64 + i * 16 + fm) * 64 + s * 32 + fk);
      for (int j = 0; j < 4; ++j)
        bfr[j] = *(const bf16x8*)(Bs + (wc * 64 + j * 16 + fm) * 64 + s * 32 + fk);
      for (int i = 0; i < 4; ++i)
        for (int j = 0; j < 4; ++j)
          acc[i][j] = __builtin_amdgcn_mfma_f32_16x16x32_bf16(af[i], bfr[j],
                                                              acc[i][j], 0, 0, 0);
    }
    __syncthreads();
  }

  // stage full 128x128 bf16 tile (pitch 136; 34.8KB fits the 48KB smem)
  u16* Cs = smem;
  for (int i = 0; i < 4; ++i)
    for (int j = 0; j < 4; ++j)
      for (int r = 0; r < 4; ++r)
        Cs[(wr * 64 + i * 16 + quad * 4 + r) * 136 + wc * 64 + j * 16 + fm] =
            f2bf(acc[i][j][r]);
  __syncthreads();

  const int head = blockIdx.x;
  const int b = m0 >> 11, l0 = m0 & 2047;
  if (head < 20) {
    // RMSnorm + RoPE. Row = token; each row processed by a 32-lane half-wave,
    // lane sl owns cols 4sl..4sl+3. rotate_half partner block = sl^16.
    const int isq = head < 16;
    const float* wv = isq ? qw : kw;
    const int half = lane >> 5, sl = lane & 31;
    u16* outp = isq ? (Qb + (size_t)(b * H_ + head) * L_ * D_)
                    : (Kb + (size_t)(b * KV_ + head - 16) * L_ * D_);
    const float4 wvv = *(const float4*)(wv + sl * 4);
    for (int it = 0; it < 16; ++it) {
      int r = wave * 32 + it * 2 + half;
      const u16* crow = Cs + r * 136 + sl * 4;
      u32 c01 = *(const u32*)crow;
      u32 c23 = *(const u32*)(crow + 2);
      float x0 = bf2f((u16)(c01 & 0xffff)), x1 = bf2f((u16)(c01 >> 16));
      float x2 = bf2f((u16)(c23 & 0xffff)), x3 = bf2f((u16)(c23 >> 16));
      float ssq = (x0 * x0 + x1 * x1) + (x2 * x2 + x3 * x3);
      ssq += __shfl_xor(ssq, 1);
      ssq += __shfl_xor(ssq, 2);
      ssq += __shfl_xor(ssq, 4);
      ssq += __shfl_xor(ssq, 8);
      ssq += __shfl_xor(ssq, 16);
      float rr = rsqrtf(ssq * (1.0f / 128.0f) + 1e-6f);
      float n0 = x0 * rr * wvv.x, n1 = x1 * rr * wvv.y;
      float n2 = x2 * rr * wvv.z, n3 = x3 * rr * wvv.w;
      float p0 = __shfl_xor(n0, 16), p1 = __shfl_xor(n1, 16);
      float p2 = __shfl_xor(n2, 16), p3 = __shfl_xor(n3, 16);
      float sgn = (sl < 16) ? -1.0f : 1.0f;
      int tok = m0 + r;
      const float4 cv = *(const float4*)(cosp + (size_t)tok * 128 + sl * 4);
      const float4 sv = *(const float4*)(sinp + (size_t)tok * 128 + sl * 4);
      float o0 = n0 * cv.x + sgn * p0 * sv.x;
      float o1 = n1 * cv.y + sgn * p1 * sv.y;
      float o2 = n2 * cv.z + sgn * p2 * sv.z;
      float o3 = n3 * cv.w + sgn * p3 * sv.w;
      if (isq) { o0 *= QSCALE; o1 *= QSCALE; o2 *= QSCALE; o3 *= QSCALE; }
      u32 lo = (u32)f2bf(o0) | ((u32)f2bf(o1) << 16);
      u32 hi = (u32)f2bf(o2) | ((u32)f2bf(o3) << 16);
      *(uint2*)(outp + (size_t)(l0 + r) * D_ + sl * 4) = make_uint2(lo, hi);
    }
  } else {
    // V: transpose to (B,KV,D,L) with the key-permutation within 32-token
    // groups (l = 32a+16b2+4c+d2 -> lp = 32a+8c+4b2+d2) for b128 PV frags.
    int g = head - 20;
    int d = tid >> 1, lh = tid & 1;  // lh = 64-token half of this 128-tile
    u16* dst = Vtb + ((size_t)(b * KV_ + g) * D_ + d) * L_ + l0 + lh * 64;
    for (int a2 = 0; a2 < 2; ++a2)
      for (int bc = 0; bc < 8; ++bc) {
        int b2 = bc & 1, c = bc >> 1;
        int ls = lh * 64 + a2 * 32 + 16 * b2 + 4 * c;
        u32 lo = (u32)Cs[ls * 136 + d] | ((u32)Cs[(ls + 1) * 136 + d] << 16);
        u32 hi = (u32)Cs[(ls + 2) * 136 + d] | ((u32)Cs[(ls + 3) * 136 + d] << 16);
        *(uint2*)(dst + a2 * 32 + 8 * c + 4 * b2) = make_uint2(lo, hi);
      }
  }
}

// ---------------- bf16 GEMM: C(MxN) = A(MxK) @ Bt(NxK)^T, fp32 out ----------------
template <int OUT_BF16>
__global__ __launch_bounds__(256, 3) void k_gemm_bt(
    const u16* __restrict__ A, const u16* __restrict__ Bt, void* __restrict__ Cv,
    int M, int N, int K) {
  __shared__ u16 smem[16384];
  u16* As = smem;
  u16* Bs = smem + 8192;
  const int tid = threadIdx.x;
  const int wave = tid >> 6, lane = tid & 63;
  const int wr = wave >> 1, wc = wave & 1;
  const int quad = lane >> 4, fm = lane & 15;
  const int m0 = blockIdx.y * 128, n0 = blockIdx.x * 128;
  f32x4 acc[4][4];
  for (int i = 0; i < 4; ++i)
    for (int j = 0; j < 4; ++j)
      for (int r = 0; r < 4; ++r) acc[i][j][r] = 0.0f;

  const int lrow = lane >> 3;
  const int lcol = (lane & 7) * 8;
  const int fk = quad * 8;

  for (int kt = 0; kt < K; kt += 64) {
    for (int p = 0; p < 4; ++p) {
      int roff = wave * 32 + p * 8 + lrow;
      gl_lds16(A + (size_t)(m0 + roff) * K + kt + lcol,
               As + wave * 2048 + p * 512 + lane * 8);
      gl_lds16(Bt + (size_t)(n0 + roff) * K + kt + lcol,
               Bs + wave * 2048 + p * 512 + lane * 8);
    }
    __syncthreads();
    for (int s = 0; s < 2; ++s) {
      bf16x8 af[4], bfr[4];
      for (int i = 0; i < 4; ++i)
        af[i] = *(const bf16x8*)(As + (wr * 64 + i * 16 + fm) * 64 + s * 32 + fk);
      for (int j = 0; j < 4; ++j)
        bfr[j] = *(const bf16x8*)(Bs + (wc * 64 + j * 16 + fm) * 64 + s * 32 + fk);
      for (int i = 0; i < 4; ++i)
        for (int j = 0; j < 4; ++j)
          acc[i][j] = __builtin_amdgcn_mfma_f32_16x16x32_bf16(af[i], bfr[j],
                                                              acc[i][j], 0, 0, 0);
    }
    __syncthreads();
  }

  if (OUT_BF16) {
    u16* Cs = smem;
    for (int hh = 0; hh < 2; ++hh) {
      if (hh) __syncthreads();
      if (wr == hh)
        for (int i = 0; i < 4; ++i)
          for (int j = 0; j < 4; ++j)
            for (int r = 0; r < 4; ++r)
              Cs[(i * 16 + quad * 4 + r) * 136 + wc * 64 + j * 16 + fm] =
                  f2bf(acc[i][j][r]);
      __syncthreads();
      for (int it = 0; it < 4; ++it) {
        int row = it * 16 + (tid >> 4);
        int col = (tid & 15) * 8;
        uint4 v = *(const uint4*)(Cs + row * 136 + col);
        *(uint4*)((u16*)Cv + (size_t)(m0 + hh * 64 + row) * N + n0 + col) = v;
      }
    }
  } else {
    float* Cf = (float*)smem;
    for (int p = 0; p < 4; ++p) {
      if (p) __syncthreads();
      if (wr == (p >> 1))
        for (int ii = 0; ii < 2; ++ii) {
          int i = 2 * (p & 1) + ii;
          for (int j = 0; j < 4; ++j)
            for (int r = 0; r < 4; ++r)
              Cf[(ii * 16 + quad * 4 + r) * 132 + wc * 64 + j * 16 + fm] =
                  acc[i][j][r];
        }
      __syncthreads();
      for (int it = 0; it < 4; ++it) {
        int row = it * 8 + (tid >> 5);
        int col = (tid & 31) * 4;
        float4 v = *(const float4*)(Cf + row * 132 + col);
        *(float4*)((float*)Cv + (size_t)(m0 + p * 32 + row) * N + n0 + col) = v;
      }
    }
  }
}

// ---------------- flash attention (S^T, no-max softmax, 2 groups/wave, dbuf) ----------------
__global__ __launch_bounds__(256, 2) void k_attn(const u16* __restrict__ Qb,
                                                 const u16* __restrict__ Kb,
                                                 const u16* __restrict__ Vtb,
                                                 u16* __restrict__ AO) {
  __shared__ u16 smem[32768];
  const int tid = threadIdx.x, wave = tid >> 6, lane = tid & 63;
  const int quad = lane >> 4, fm = lane & 15;
  const int f7 = fm & 7;
  const int qt = blockIdx.x, bh = blockIdx.y;
  const int b = bh >> 4, h = bh & 15, g = h >> 2;
  const u16* Kg = Kb + ((size_t)(b * KV_ + g)) * L_ * D_;
  const u16* Vg = Vtb + ((size_t)(b * KV_ + g)) * D_ * L_;

  const u16* Qg = Qb + ((size_t)bh * L_ + qt * 128 + wave * 32 + fm) * D_;
  bf16x8 qf1[4], qf2[4];
  for (int ks = 0; ks < 4; ++ks) {
    qf1[ks] = *(const bf16x8*)(Qg + ks * 32 + quad * 8);
    qf2[ks] = *(const bf16x8*)(Qg + 16 * D_ + ks * 32 + quad * 8);
  }

  f32x4 o1[8], o2[8];
  for (int f = 0; f < 8; ++f)
    for (int r = 0; r < 4; ++r) { o1[f][r] = 0.0f; o2[f][r] = 0.0f; }
  float lr1 = 0.0f, lr2 = 0.0f;
  const f32x4 fz = {0.0f, 0.0f, 0.0f, 0.0f};

  const int eK = wave * 2048 + (lane << 3);
  const int cK = lane & 15;
  const int cV = lane & 7;

#define STAGE(kt_, buf_)                                                      \
  {                                                                           \
    u16* Kd = smem + (buf_)*16384;                                            \
    u16* Vd = smem + (buf_)*16384 + 8192;                                     \
    for (int p = 0; p < 4; ++p) {                                             \
      int e = eK + p * 512;                                                   \
      int rowK = e >> 7;                                                      \
      int gK = (cK & 8) | ((cK & 7) ^ (rowK & 7));                            \
      gl_lds16(Kg + (size_t)((kt_)*64 + rowK) * 128 + gK * 8, Kd + e);        \
      int rowV = e >> 6;                                                      \
      int gV = cV ^ (rowV & 7);                                               \
      gl_lds16(Vg + (size_t)rowV * L_ + (kt_)*64 + gV * 8, Vd + e);           \
    }                                                                         \
  }

  STAGE(0, 0);
  for (int kt = 0; kt < 32; ++kt) {
    __syncthreads();
    if (kt + 1 < 32) STAGE(kt + 1, (kt + 1) & 1);
    const u16* Ks = smem + (kt & 1) * 16384;
    const u16* Vs = Ks + 8192;

    // S^T = K Q^T : ks=0 initializes via zero C-operand (no mov-zero init)
    f32x4 s1[4], s2[4];
    {
      int cp = (quad & 8) | (quad ^ f7);  // c = quad for ks=0
      for (int n = 0; n < 4; ++n) {
        bf16x8 kf = *(const bf16x8*)(Ks + (n * 16 + fm) * 128 + cp * 8);
        s1[n] = __builtin_amdgcn_mfma_f32_16x16x32_bf16(kf, qf1[0], fz, 0, 0, 0);
        s2[n] = __builtin_amdgcn_mfma_f32_16x16x32_bf16(kf, qf2[0], fz, 0, 0, 0);
      }
    }
    for (int ks = 1; ks < 4; ++ks) {
      int c = 4 * ks + quad;
      int cp = (c & 8) | ((c & 7) ^ f7);
      for (int n = 0; n < 4; ++n) {
        bf16x8 kf = *(const bf16x8*)(Ks + (n * 16 + fm) * 128 + cp * 8);
        s1[n] = __builtin_amdgcn_mfma_f32_16x16x32_bf16(kf, qf1[ks], s1[n], 0, 0, 0);
        s2[n] = __builtin_amdgcn_mfma_f32_16x16x32_bf16(kf, qf2[ks], s2[n], 0, 0, 0);
      }
    }

    // softmax without max subtraction: P = 2^s (bounded, scale cancels)
    u32 pk1[4][2], pk2[4][2];
    float rs1 = 0.0f, rs2 = 0.0f;
    for (int n = 0; n < 4; ++n) {
      float a0 = __builtin_amdgcn_exp2f(s1[n][0]);
      float a1 = __builtin_amdgcn_exp2f(s1[n][1]);
      float a2 = __builtin_amdgcn_exp2f(s1[n][2]);
      float a3 = __builtin_amdgcn_exp2f(s1[n][3]);
      rs1 += (a0 + a1) + (a2 + a3);
      pk1[n][0] = pkbf(a0, a1);
      pk1[n][1] = pkbf(a2, a3);
      float b0 = __builtin_amdgcn_exp2f(s2[n][0]);
      float b1 = __builtin_amdgcn_exp2f(s2[n][1]);
      float b2 = __builtin_amdgcn_exp2f(s2[n][2]);
      float b3 = __builtin_amdgcn_exp2f(s2[n][3]);
      rs2 += (b0 + b1) + (b2 + b3);
      pk2[n][0] = pkbf(b0, b1);
      pk2[n][1] = pkbf(b2, b3);
    }
    lr1 += rs1;
    lr2 += rs2;

    // O += P V via K=32 bf16: each vv load feeds both groups
    for (int ks2 = 0; ks2 < 2; ++ks2) {
      union { u32 u[4]; bf16x8 v; } pa1, pa2;
      pa1.u[0] = pk1[2 * ks2][0];
      pa1.u[1] = pk1[2 * ks2][1];
      pa1.u[2] = pk1[2 * ks2 + 1][0];
      pa1.u[3] = pk1[2 * ks2 + 1][1];
      pa2.u[0] = pk2[2 * ks2][0];
      pa2.u[1] = pk2[2 * ks2][1];
      pa2.u[2] = pk2[2 * ks2 + 1][0];
      pa2.u[3] = pk2[2 * ks2 + 1][1];
      int chunk = (4 * ks2 + quad) ^ f7;
      for (int f = 0; f < 8; ++f) {
        bf16x8 vv = *(const bf16x8*)(Vs + (f * 16 + fm) * 64 + chunk * 8);
        o1[f] = __builtin_amdgcn_mfma_f32_16x16x32_bf16(pa1.v, vv, o1[f], 0, 0, 0);
        o2[f] = __builtin_amdgcn_mfma_f32_16x16x32_bf16(pa2.v, vv, o2[f], 0, 0, 0);
      }
    }
  }
#undef STAGE

  // epilogue
  const size_t tok0 = (size_t)b * L_ + qt * 128;
  for (int grp = 0; grp < 2; ++grp) {
    f32x4* o = grp ? o2 : o1;
    float lr = grp ? lr2 : lr1;
    lr += __shfl_xor(lr, 16);
    lr += __shfl_xor(lr, 32);
    float li = 1.0f / lr;
    float l0 = __shfl(li, (lane & 48) | (quad * 4 + 0));
    float l1 = __shfl(li, (lane & 48) | (quad * 4 + 1));
    float l2 = __shfl(li, (lane & 48) | (quad * 4 + 2));
    float l3 = __shfl(li, (lane & 48) | (quad * 4 + 3));
    __syncthreads();
    for (int f = 0; f < 8; ++f) {
      int e = (wave * 16 + quad * 4) * 136 + f * 16 + fm;
      smem[e] = f2bf(o[f][0] * l0);
      smem[e + 136] = f2bf(o[f][1] * l1);
      smem[e + 272] = f2bf(o[f][2] * l2);
      smem[e + 408] = f2bf(o[f][3] * l3);
    }
    __syncthreads();
    for (int it = 0; it < 8; ++it) {
      int crow = (tid >> 6) * 16 + it * 2 + (lane >> 5);
      int q = (crow >> 4) * 32 + grp * 16 + (crow & 15);
      int cc = (lane & 31) * 4;
      uint2 v = *(const uint2*)(smem + crow * 136 + cc);
      *(uint2*)(AO + (tok0 + q) * (H_ * D_) + h * D_ + cc) = v;
    }
  }
}

// ---------------- launcher ----------------
extern "C" void kernel_launch(void* const* d_in, const int* in_sizes, int n_in,
                              void* d_out, int out_size, void* d_ws,
                              size_t ws_size, hipStream_t stream) {
  const float* hidden = (const float*)d_in[0];
  const float* cosp = (const float*)d_in[1];
  const float* sinp = (const float*)d_in[2];
  const float* Wq = (const float*)d_in[3];
  const float* Wk = (const float*)d_in[4];
  const float* Wv = (const float*)d_in[5];
  const float* Wo = (const float*)d_in[6];
  const float* qw = (const float*)d_in[7];
  const float* kw = (const float*)d_in[8];
  float* out = (float*)d_out;

  char* w = (char*)d_ws;
  u16* Xb = (u16*)(w);                          // 4096x2048 bf16, 16MB
  u16* Wtqkv = (u16*)(w + (16u << 20));         // 3072x2048 bf16, 12MB
  u16* Wto = (u16*)(w + (28u << 20));           // 2048x2048 bf16, 8MB
  u16* Qb = (u16*)(w + (36u << 20));            // 16MB
  u16* Kb = (u16*)(w + (52u << 20));            // 4MB
  u16* Vtb = (u16*)(w + (56u << 20));           // 4MB (ends 60MB)
  u16* AO = Xb;                                 // reuse after gemm_qkv

  k_prep<<<18432, 256, 0, stream>>>(hidden, Xb, Wq, Wk, Wv, Wo, Wtqkv, Wto);
  k_gemm_qkv<<<dim3(24, 32), 256, 0, stream>>>(Xb, Wtqkv, cosp, sinp, qw, kw,
                                               Qb, Kb, Vtb);
  k_attn<<<dim3(16, 32), 256, 0, stream>>>(Qb, Kb, Vtb, AO);
  k_gemm_bt<0><<<dim3(16, 32), 256, 0, stream>>>(AO, Wto, out, 4096, 2048, 2048);
}